// Round 1
// baseline (1676.702 us; speedup 1.0000x reference)
//
#include <hip/hip_runtime.h>
#include <hip/hip_bf16.h>

// Problem constants
#define BB 32
#define VV 2562
#define HH 192
#define CIN_ 966
#define KP1 992            // 966 padded to multiple of 32 (zero-filled tail)
#define PD 963
#define MROWS (BB * VV)    // 81984
#define MP 82048           // 641 * 128 (row-padded M)
#define NBLK 641

typedef __attribute__((ext_vector_type(8))) short short8;
typedef __attribute__((ext_vector_type(4))) float floatx4;
using bf16 = __hip_bfloat16;

static __device__ __forceinline__ float b2f(bf16 x) { return __bfloat162float(x); }
static __device__ __forceinline__ bf16  f2b(float x) { return __float2bfloat16(x); }
static __device__ __forceinline__ float ldS(const float* p, size_t i) { return p[i]; }
static __device__ __forceinline__ float ldS(const bf16*  p, size_t i) { return b2f(p[i]); }
static __device__ __forceinline__ void store_out(float* p, float v) { *p = v; }
static __device__ __forceinline__ void store_out(bf16*  p, float v) { *p = f2b(v); }

// ---------------------------------------------------------------------------
// CSR build: adj is dense [V,V] 0/1 fp32 with self loops, degree <= 7.
__global__ void k_csr(const float* __restrict__ adj, int* __restrict__ degs,
                      int* __restrict__ cols, float* __restrict__ invn) {
    int u = blockIdx.x;
    __shared__ int cnt;
    if (threadIdx.x == 0) cnt = 0;
    __syncthreads();
    for (int j = threadIdx.x; j < VV; j += blockDim.x) {
        if (adj[(size_t)u * VV + j] != 0.0f) {
            int p = atomicAdd(&cnt, 1);
            if (p < 8) cols[u * 8 + p] = j;
        }
    }
    __syncthreads();
    if (threadIdx.x == 0) {
        degs[u] = (cnt < 8) ? cnt : 8;
        invn[u] = (cnt > 0) ? (1.0f / (float)cnt) : 0.0f;  // guard: no inf
    }
}

// ---------------------------------------------------------------------------
// Weight prep (fp32 -> bf16, transposed): W1t[n][k] (k padded to 992, zero
// tail), Wmt[l][n][k] from Wm[l][k][n].
__global__ void k_trans(const float* __restrict__ W1, const float* __restrict__ Wm,
                        bf16* __restrict__ W1t, bf16* __restrict__ Wmt) {
    int idx = blockIdx.x * 256 + threadIdx.x;
    const int n1 = HH * KP1;
    if (idx < n1) {
        int n = idx / KP1, k = idx % KP1;
        W1t[idx] = (k < CIN_) ? f2b(W1[(size_t)k * HH + n]) : f2b(0.0f);
    } else {
        int t = idx - n1;
        if (t < 12 * HH * HH) {
            int l = t / (HH * HH);
            int r = t % (HH * HH);
            int n = r / HH, k = r % HH;
            Wmt[t] = f2b(Wm[(size_t)l * HH * HH + (size_t)k * HH + n]);
        }
    }
}

// ---------------------------------------------------------------------------
// Materialize full = concat(features, pooled) [MROWS][992] as bf16, zero tail.
__global__ void k_fill(const float* __restrict__ feat, const float* __restrict__ pooled,
                       bf16* __restrict__ full) {
    const int CPR = KP1 / 8;  // 124 aligned 8-elem chunks per row
    int idx = blockIdx.x * 256 + threadIdx.x;
    if (idx >= MROWS * CPR) return;
    int row = idx / CPR;
    int c0  = (idx % CPR) * 8;
    union { bf16 h[8]; short8 v; } tmp;
#pragma unroll
    for (int j = 0; j < 8; j++) {
        int c = c0 + j;
        float v;
        if (c < 3)          v = feat[(size_t)row * 3 + c];
        else if (c < CIN_)  v = pooled[(size_t)row * PD + (c - 3)];
        else                v = 0.0f;
        tmp.h[j] = f2b(v);
    }
    *(short8*)(&full[(size_t)row * KP1 + c0]) = tmp.v;
}

// ---------------------------------------------------------------------------
// GEMM: C[MP x 192] = A[MP x K](bf16) * W[K x 192](bf16, transposed Bt[n][k]).
// Block tile 128 x 192, BK=32, 4 waves: wave w covers n in [48w,48w+48)
// (3 n-tiles) x all 8 m-tiles.  A staged in LDS (stride 40 -> 2-way bank
// aliasing only, free per m136).  B frags from global (L2-resident).
template <typename OutT>
__global__ __launch_bounds__(256) void k_gemm(const bf16* __restrict__ A, int lda,
                                              const bf16* __restrict__ Bt, int ldb, int K,
                                              OutT* __restrict__ C) {
    __shared__ bf16 As[128][40];
    const int tid  = threadIdx.x;
    const int wave = tid >> 6, lane = tid & 63;
    const int quad = lane >> 4, l15 = lane & 15;
    const size_t m0 = (size_t)blockIdx.x * 128;

    floatx4 acc[8][3];
#pragma unroll
    for (int i = 0; i < 8; i++)
#pragma unroll
        for (int j = 0; j < 3; j++) acc[i][j] = (floatx4){0.f, 0.f, 0.f, 0.f};

    const int r0 = tid >> 2;        // 0..63
    const int k8 = (tid & 3) * 8;   // 0,8,16,24

    for (int k0 = 0; k0 < K; k0 += 32) {
        __syncthreads();
        *(short8*)(&As[r0][k8])      = *(const short8*)(A + (m0 + r0)      * (size_t)lda + k0 + k8);
        *(short8*)(&As[r0 + 64][k8]) = *(const short8*)(A + (m0 + r0 + 64) * (size_t)lda + k0 + k8);
        __syncthreads();
        short8 bfr[3];
#pragma unroll
        for (int nt = 0; nt < 3; nt++) {
            int n = wave * 48 + nt * 16 + l15;
            bfr[nt] = *(const short8*)(Bt + (size_t)n * ldb + k0 + quad * 8);
        }
#pragma unroll
        for (int mt = 0; mt < 8; mt++) {
            short8 afr = *(const short8*)(&As[mt * 16 + l15][quad * 8]);
#pragma unroll
            for (int nt = 0; nt < 3; nt++)
                acc[mt][nt] = __builtin_amdgcn_mfma_f32_16x16x32_bf16(afr, bfr[nt], acc[mt][nt], 0, 0, 0);
        }
    }
    // Epilogue: D row = quad*4 + r, col = l15 (m89-verified C/D layout)
#pragma unroll
    for (int mt = 0; mt < 8; mt++) {
#pragma unroll
        for (int nt = 0; nt < 3; nt++) {
            int n = wave * 48 + nt * 16 + l15;
#pragma unroll
            for (int r = 0; r < 4; r++) {
                size_t row = m0 + mt * 16 + quad * 4 + r;
                store_out(C + row * HH + n, acc[mt][nt][r]);
            }
        }
    }
}

// ---------------------------------------------------------------------------
// Fused: sparse-aggregate + concat-reorder + bias  ->  BN(per-vertex over B,C)
// -> relu -> (store x | residual update).  One block per vertex u.
// MODE 0: write x (bf16) only.
// MODE 1: feats = (full[:, :192] + x)/2  (reads features/pooled fp32).
// MODE 2: feats = (feats + x)/2.
// MODE 3: MODE 2 + write feats to d_out (fp32).
template <typename ST, int MODE>
__global__ __launch_bounds__(256) void k_bn(const ST* __restrict__ S,
                                            const int* __restrict__ degs, const int* __restrict__ cols,
                                            const float* __restrict__ invn,
                                            const float* __restrict__ bias,
                                            const float* __restrict__ gamma, const float* __restrict__ beta,
                                            const float* __restrict__ feat3, const float* __restrict__ pooled,
                                            float* __restrict__ featsF, bf16* __restrict__ featsB,
                                            bf16* __restrict__ xout, float* __restrict__ dOut) {
    const int u = blockIdx.x;
    const int tid = threadIdx.x;
    __shared__ float red[4];

    const int deg = degs[u];
    int vc[8]; float vi[8];
#pragma unroll
    for (int j = 0; j < 8; j++) {
        if (j < deg) { vc[j] = cols[u * 8 + j]; vi[j] = invn[vc[j]]; }
        else         { vc[j] = 0;               vi[j] = 0.0f; }      // 0 * finite = 0
    }

    float yv[24];
    float psum = 0.0f;
#pragma unroll
    for (int it = 0; it < 24; it++) {
        int i = tid + it * 256;
        int b = i / HH, c = i % HH;    // each (wave,it) is branch-uniform
        size_t base = (size_t)b * VV * HH;
        float v = bias[c];
        if (c < 128) {
            v += ldS(S, base + (size_t)u * HH + 64 + c);
        } else {
            int d = c - 128;
#pragma unroll
            for (int j = 0; j < 8; j++)
                v += vi[j] * ldS(S, base + (size_t)vc[j] * HH + d);
        }
        yv[it] = v;
        psum += v;
    }
    // block reduce (sum)
#pragma unroll
    for (int off = 32; off; off >>= 1) psum += __shfl_down(psum, off, 64);
    if ((tid & 63) == 0) red[tid >> 6] = psum;
    __syncthreads();
    const float mean = (red[0] + red[1] + red[2] + red[3]) * (1.0f / (BB * HH));
    __syncthreads();
    float pvar = 0.0f;
#pragma unroll
    for (int it = 0; it < 24; it++) { float t = yv[it] - mean; pvar += t * t; }
#pragma unroll
    for (int off = 32; off; off >>= 1) pvar += __shfl_down(pvar, off, 64);
    if ((tid & 63) == 0) red[tid >> 6] = pvar;
    __syncthreads();
    const float rstd = rsqrtf((red[0] + red[1] + red[2] + red[3]) * (1.0f / (BB * HH)) + 1e-5f);
    const float ga = gamma[u], be = beta[u];

#pragma unroll
    for (int it = 0; it < 24; it++) {
        int i = tid + it * 256;
        int b = i / HH, c = i % HH;
        size_t row = (size_t)b * VV + u;
        float o = fmaxf(ga * (yv[it] - mean) * rstd + be, 0.0f);
        if constexpr (MODE == 0) {
            xout[row * HH + c] = f2b(o);
        } else {
            float f;
            if constexpr (MODE == 1)
                f = (c < 3) ? feat3[row * 3 + c] : pooled[row * PD + (c - 3)];
            else
                f = featsF[row * HH + c];
            float fn = (f + o) * 0.5f;
            featsF[row * HH + c] = fn;
            featsB[row * HH + c] = f2b(fn);
            if constexpr (MODE == 3) dOut[row * HH + c] = fn;
        }
    }
}

// ---------------------------------------------------------------------------
// coords support: SC[row][3] = feats[row][:] @ W15[192][3] (tiny GEMM)
__global__ __launch_bounds__(256) void k_cgemm(const bf16* __restrict__ F,
                                               const float* __restrict__ W15,
                                               float* __restrict__ SC) {
    __shared__ bf16 fs[128 * HH];
    const size_t m0 = (size_t)blockIdx.x * 128;
    const int tid = threadIdx.x;
    for (int c = tid; c < 128 * HH / 8; c += 256) {
        int row = c / 24, c8 = (c % 24) * 8;
        *(short8*)(&fs[row * HH + c8]) = *(const short8*)(F + (m0 + row) * HH + c8);
    }
    __syncthreads();
    for (int idx = tid; idx < 128 * 3; idx += 256) {
        int row = idx / 3, o = idx % 3;
        float acc = 0.0f;
        for (int k = 0; k < HH; k++)
            acc += b2f(fs[row * HH + k]) * W15[k * 3 + o];
        if (m0 + row < MROWS) SC[(m0 + row) * 3 + o] = acc;
    }
}

// coords: ch0 = SC[:,2]+b15[0]; ch1/2 = sparse-agg of SC[:,0]/SC[:,1] + b15[1/2]
__global__ void k_cagg(const float* __restrict__ SC, const int* __restrict__ degs,
                       const int* __restrict__ cols, const float* __restrict__ invn,
                       const float* __restrict__ b15, float* __restrict__ out) {
    int gid = blockIdx.x * 256 + threadIdx.x;
    if (gid >= MROWS) return;
    int u = gid % VV;
    int b = gid / VV;
    int deg = degs[u];
    float s0 = 0.0f, s1 = 0.0f;
#pragma unroll
    for (int j = 0; j < 8; j++) {
        if (j < deg) {
            int v = cols[u * 8 + j];
            float w = invn[v];
            s0 += w * SC[((size_t)b * VV + v) * 3 + 0];
            s1 += w * SC[((size_t)b * VV + v) * 3 + 1];
        }
    }
    out[(size_t)gid * 3 + 0] = SC[(size_t)gid * 3 + 2] + b15[0];
    out[(size_t)gid * 3 + 1] = s0 + b15[1];
    out[(size_t)gid * 3 + 2] = s1 + b15[2];
}

// ---------------------------------------------------------------------------
extern "C" void kernel_launch(void* const* d_in, const int* in_sizes, int n_in,
                              void* d_out, int out_size, void* d_ws, size_t ws_size,
                              hipStream_t stream) {
    const float* feat   = (const float*)d_in[0];
    const float* pooled = (const float*)d_in[1];
    const float* adj    = (const float*)d_in[2];
    const float* W1     = (const float*)d_in[3];
    const float* b1     = (const float*)d_in[4];
    const float* Wm     = (const float*)d_in[5];
    const float* bm     = (const float*)d_in[6];
    const float* W15    = (const float*)d_in[7];
    const float* b15    = (const float*)d_in[8];
    const float* gamma  = (const float*)d_in[9];
    const float* beta   = (const float*)d_in[10];
    float* outF = (float*)d_out;                    // feats [B,V,192] fp32
    float* outC = outF + (size_t)MROWS * HH;        // coords [B,V,3] fp32

    char* ws = (char*)d_ws;
    size_t off = 0;
    auto alloc = [&](size_t bytes) -> void* {
        void* p = ws + off;
        off = (off + bytes + 255) & ~(size_t)255;
        return p;
    };
    // Region A (MP*1984 B): full(bf16) lives here for GEMM1 only; afterwards
    // featsF [0, MP*768), sF [MP*768, MP*1536), xB [MP*1536, MP*1920) overlap
    // it (fullB is dead before xB's first write).
    char* regionA = (char*)alloc((size_t)MP * KP1 * 2);
    bf16*  fullB  = (bf16*)regionA;
    float* featsF = (float*)regionA;
    float* sF     = (float*)(regionA + (size_t)MP * HH * 4);
    bf16*  xB     = (bf16*) (regionA + (size_t)MP * HH * 8);
    bf16*  featsB = (bf16*)alloc((size_t)MP * HH * 2);
    bf16*  W1t    = (bf16*)alloc((size_t)HH * KP1 * 2);
    bf16*  Wmt    = (bf16*)alloc((size_t)12 * HH * HH * 2);
    float* SC     = (float*)alloc((size_t)MP * 3 * 4);
    int*   degs   = (int*)alloc(VV * 4);
    int*   colsp  = (int*)alloc(VV * 8 * 4);
    float* invn   = (float*)alloc(VV * 4);
    (void)ws_size; (void)in_sizes; (void)n_in; (void)out_size;

    k_csr<<<VV, 256, 0, stream>>>(adj, degs, colsp, invn);
    int ntr = (HH * KP1 + 12 * HH * HH + 255) / 256;
    k_trans<<<ntr, 256, 0, stream>>>(W1, Wm, W1t, Wmt);
    int nfill = (MROWS * (KP1 / 8) + 255) / 256;
    k_fill<<<nfill, 256, 0, stream>>>(feat, pooled, fullB);

    // layer 1: gc1 (K=992 padded).  supp -> featsB (bf16) while fullB alive.
    k_gemm<bf16><<<NBLK, 256, 0, stream>>>(fullB, KP1, W1t, KP1, KP1, featsB);
    k_bn<bf16, 0><<<VV, 256, 0, stream>>>(featsB, degs, colsp, invn, b1,
                                          gamma + 0 * VV, beta + 0 * VV,
                                          nullptr, nullptr, nullptr, nullptr, xB, nullptr);
    // layer 2: gc2 + residual init  feats = (full[:, :192] + x)/2
    k_gemm<float><<<NBLK, 256, 0, stream>>>(xB, HH, Wmt, HH, HH, sF);
    k_bn<float, 1><<<VV, 256, 0, stream>>>(sF, degs, colsp, invn, bm,
                                           gamma + 1 * VV, beta + 1 * VV,
                                           feat, pooled, featsF, featsB, nullptr, nullptr);
    // five residual pairs
    for (int i = 0; i < 5; i++) {
        int la = 2 * i + 1, lb = 2 * i + 2;
        k_gemm<float><<<NBLK, 256, 0, stream>>>(featsB, HH, Wmt + (size_t)la * HH * HH, HH, HH, sF);
        k_bn<float, 0><<<VV, 256, 0, stream>>>(sF, degs, colsp, invn, bm + la * HH,
                                               gamma + (size_t)(la + 1) * VV, beta + (size_t)(la + 1) * VV,
                                               nullptr, nullptr, nullptr, nullptr, xB, nullptr);
        k_gemm<float><<<NBLK, 256, 0, stream>>>(xB, HH, Wmt + (size_t)lb * HH * HH, HH, HH, sF);
        k_bn<float, 2><<<VV, 256, 0, stream>>>(sF, degs, colsp, invn, bm + lb * HH,
                                               gamma + (size_t)(lb + 1) * VV, beta + (size_t)(lb + 1) * VV,
                                               nullptr, nullptr, featsF, featsB, nullptr, nullptr);
    }
    // gc13 + final residual (also writes feats to d_out, fp32)
    k_gemm<float><<<NBLK, 256, 0, stream>>>(featsB, HH, Wmt + (size_t)11 * HH * HH, HH, HH, sF);
    k_bn<float, 3><<<VV, 256, 0, stream>>>(sF, degs, colsp, invn, bm + 11 * HH,
                                           gamma + (size_t)12 * VV, beta + (size_t)12 * VV,
                                           nullptr, nullptr, featsF, featsB, nullptr, outF);
    // coords head
    k_cgemm<<<NBLK, 256, 0, stream>>>(featsB, W15, SC);
    k_cagg<<<(MROWS + 255) / 256, 256, 0, stream>>>(SC, degs, colsp, invn, b15, outC);
}

// Round 2
// 1550.164 us; speedup vs baseline: 1.0816x; 1.0816x over previous
//
#include <hip/hip_runtime.h>
#include <hip/hip_bf16.h>

// Problem constants
#define BB 32
#define VV 2562
#define HH 192
#define CIN_ 966
#define KP1 992            // 966 padded to multiple of 32 (zero-filled tail)
#define PD 963
#define MROWS (BB * VV)    // 81984
#define MP 82048           // 641 * 128 (row-padded M)
#define NBLK 641

typedef __attribute__((ext_vector_type(8))) short short8;
typedef __attribute__((ext_vector_type(4))) float floatx4;
using bf16 = __hip_bfloat16;

static __device__ __forceinline__ float b2f(bf16 x) { return __bfloat162float(x); }
static __device__ __forceinline__ bf16  f2b(float x) { return __float2bfloat16(x); }
static __device__ __forceinline__ float ldS(const float* p, size_t i) { return p[i]; }
static __device__ __forceinline__ float ldS(const bf16*  p, size_t i) { return b2f(p[i]); }

// ---------------------------------------------------------------------------
// CSR build: adj is dense [V,V] 0/1 fp32 with self loops, degree <= 7.
__global__ void k_csr(const float* __restrict__ adj, int* __restrict__ degs,
                      int* __restrict__ cols, float* __restrict__ invn) {
    int u = blockIdx.x;
    __shared__ int cnt;
    if (threadIdx.x == 0) cnt = 0;
    __syncthreads();
    for (int j = threadIdx.x; j < VV; j += blockDim.x) {
        if (adj[(size_t)u * VV + j] != 0.0f) {
            int p = atomicAdd(&cnt, 1);
            if (p < 8) cols[u * 8 + p] = j;
        }
    }
    __syncthreads();
    if (threadIdx.x == 0) {
        degs[u] = (cnt < 8) ? cnt : 8;
        invn[u] = (cnt > 0) ? (1.0f / (float)cnt) : 0.0f;  // guard: no inf
    }
}

// ---------------------------------------------------------------------------
// Weight prep (fp32 -> bf16, transposed): W1t[n][k] (k padded to 992, zero
// tail), Wmt[l][n][k] from Wm[l][k][n].
__global__ void k_trans(const float* __restrict__ W1, const float* __restrict__ Wm,
                        bf16* __restrict__ W1t, bf16* __restrict__ Wmt) {
    int idx = blockIdx.x * 256 + threadIdx.x;
    const int n1 = HH * KP1;
    if (idx < n1) {
        int n = idx / KP1, k = idx % KP1;
        W1t[idx] = (k < CIN_) ? f2b(W1[(size_t)k * HH + n]) : f2b(0.0f);
    } else {
        int t = idx - n1;
        if (t < 12 * HH * HH) {
            int l = t / (HH * HH);
            int r = t % (HH * HH);
            int n = r / HH, k = r % HH;
            Wmt[t] = f2b(Wm[(size_t)l * HH * HH + (size_t)k * HH + n]);
        }
    }
}

// ---------------------------------------------------------------------------
// GEMM: C[MP x 192](bf16) = A[MP x K](bf16) * W[K x 192](bf16, Bt[n][k]).
// Block tile 128 x 192, BK=32, 4 waves: wave w covers n in [48w,48w+48)
// (3 n-tiles) x all 8 m-tiles.  A staged in LDS (stride 40 -> 2-way bank
// aliasing only, free per m136).  B frags from global (L2-resident).
__global__ __launch_bounds__(256) void k_gemm(const bf16* __restrict__ A,
                                              const bf16* __restrict__ Bt,
                                              bf16* __restrict__ C) {
    __shared__ bf16 As[128][40];
    const int tid  = threadIdx.x;
    const int wave = tid >> 6, lane = tid & 63;
    const int quad = lane >> 4, l15 = lane & 15;
    const size_t m0 = (size_t)blockIdx.x * 128;

    floatx4 acc[8][3];
#pragma unroll
    for (int i = 0; i < 8; i++)
#pragma unroll
        for (int j = 0; j < 3; j++) acc[i][j] = (floatx4){0.f, 0.f, 0.f, 0.f};

    const int r0 = tid >> 2;        // 0..63
    const int k8 = (tid & 3) * 8;   // 0,8,16,24

    for (int k0 = 0; k0 < HH; k0 += 32) {
        __syncthreads();
        *(short8*)(&As[r0][k8])      = *(const short8*)(A + (m0 + r0)      * (size_t)HH + k0 + k8);
        *(short8*)(&As[r0 + 64][k8]) = *(const short8*)(A + (m0 + r0 + 64) * (size_t)HH + k0 + k8);
        __syncthreads();
        short8 bfr[3];
#pragma unroll
        for (int nt = 0; nt < 3; nt++) {
            int n = wave * 48 + nt * 16 + l15;
            bfr[nt] = *(const short8*)(Bt + (size_t)n * HH + k0 + quad * 8);
        }
#pragma unroll
        for (int mt = 0; mt < 8; mt++) {
            short8 afr = *(const short8*)(&As[mt * 16 + l15][quad * 8]);
#pragma unroll
            for (int nt = 0; nt < 3; nt++)
                acc[mt][nt] = __builtin_amdgcn_mfma_f32_16x16x32_bf16(afr, bfr[nt], acc[mt][nt], 0, 0, 0);
        }
    }
    // Epilogue: D row = quad*4 + r, col = l15 (m89-verified C/D layout)
#pragma unroll
    for (int mt = 0; mt < 8; mt++) {
#pragma unroll
        for (int nt = 0; nt < 3; nt++) {
            int n = wave * 48 + nt * 16 + l15;
#pragma unroll
            for (int r = 0; r < 4; r++) {
                size_t row = m0 + mt * 16 + quad * 4 + r;
                C[row * HH + n] = f2b(acc[mt][nt][r]);
            }
        }
    }
}

// ---------------------------------------------------------------------------
// GEMM layer 1: A is the virtual concat(features, pooled) read directly from
// fp32 inputs (no fullB materialization), converted to bf16 during staging.
// K = KP1 (992), columns >= 966 are zero.  Rows >= MROWS clamp to row 0
// (their output lands in padded C rows that are never read).
__global__ __launch_bounds__(256) void k_gemm1(const float* __restrict__ feat,
                                               const float* __restrict__ pooled,
                                               const bf16* __restrict__ Bt,
                                               bf16* __restrict__ C) {
    __shared__ bf16 As[128][40];
    const int tid  = threadIdx.x;
    const int wave = tid >> 6, lane = tid & 63;
    const int quad = lane >> 4, l15 = lane & 15;
    const size_t m0 = (size_t)blockIdx.x * 128;

    floatx4 acc[8][3];
#pragma unroll
    for (int i = 0; i < 8; i++)
#pragma unroll
        for (int j = 0; j < 3; j++) acc[i][j] = (floatx4){0.f, 0.f, 0.f, 0.f};

    const int r0 = tid >> 2;        // 0..63
    const int k8 = (tid & 3) * 8;   // 0,8,16,24

    for (int k0 = 0; k0 < KP1; k0 += 32) {
        __syncthreads();
#pragma unroll
        for (int h = 0; h < 2; h++) {
            size_t row = m0 + r0 + h * 64;
            size_t rr  = (row < MROWS) ? row : 0;   // clamp: padded rows unused
            int c0 = k0 + k8;
            union { bf16 hh[8]; short8 v; } t;
            if (c0 >= 3 && c0 + 8 <= CIN_) {
                const float* p = pooled + rr * (size_t)PD + (c0 - 3);
#pragma unroll
                for (int j = 0; j < 8; j++) t.hh[j] = f2b(p[j]);
            } else {
#pragma unroll
                for (int j = 0; j < 8; j++) {
                    int c = c0 + j;
                    float v;
                    if (c < 3)          v = feat[rr * 3 + c];
                    else if (c < CIN_)  v = pooled[rr * (size_t)PD + (c - 3)];
                    else                v = 0.0f;
                    t.hh[j] = f2b(v);
                }
            }
            *(short8*)(&As[r0 + h * 64][k8]) = t.v;
        }
        __syncthreads();
        short8 bfr[3];
#pragma unroll
        for (int nt = 0; nt < 3; nt++) {
            int n = wave * 48 + nt * 16 + l15;
            bfr[nt] = *(const short8*)(Bt + (size_t)n * KP1 + k0 + quad * 8);
        }
#pragma unroll
        for (int mt = 0; mt < 8; mt++) {
            short8 afr = *(const short8*)(&As[mt * 16 + l15][quad * 8]);
#pragma unroll
            for (int nt = 0; nt < 3; nt++)
                acc[mt][nt] = __builtin_amdgcn_mfma_f32_16x16x32_bf16(afr, bfr[nt], acc[mt][nt], 0, 0, 0);
        }
    }
#pragma unroll
    for (int mt = 0; mt < 8; mt++) {
#pragma unroll
        for (int nt = 0; nt < 3; nt++) {
            int n = wave * 48 + nt * 16 + l15;
#pragma unroll
            for (int r = 0; r < 4; r++) {
                size_t row = m0 + mt * 16 + quad * 4 + r;
                C[row * HH + n] = f2b(acc[mt][nt][r]);
            }
        }
    }
}

// ---------------------------------------------------------------------------
// Fused: sparse-aggregate + concat-reorder + bias  ->  BN(per-vertex over B,C)
// -> relu -> (store x | residual update).  One block per vertex u.
// MODE 0: write x (bf16) only.
// MODE 1: feats = (full[:, :192] + x)/2  (reads features/pooled fp32).
// MODE 2: feats = (feats + x)/2.
// MODE 3: MODE 2 + write feats to d_out (fp32).
template <int MODE>
__global__ __launch_bounds__(256) void k_bn(const bf16* __restrict__ S,
                                            const int* __restrict__ degs, const int* __restrict__ cols,
                                            const float* __restrict__ invn,
                                            const float* __restrict__ bias,
                                            const float* __restrict__ gamma, const float* __restrict__ beta,
                                            const float* __restrict__ feat3, const float* __restrict__ pooled,
                                            float* __restrict__ featsF, bf16* __restrict__ featsB,
                                            bf16* __restrict__ xout, float* __restrict__ dOut) {
    const int u = blockIdx.x;
    const int tid = threadIdx.x;
    __shared__ float red[4];

    const int deg = degs[u];
    int vc[8]; float vi[8];
#pragma unroll
    for (int j = 0; j < 8; j++) {
        if (j < deg) { vc[j] = cols[u * 8 + j]; vi[j] = invn[vc[j]]; }
        else         { vc[j] = 0;               vi[j] = 0.0f; }      // 0 * finite = 0
    }

    float yv[24];
    float psum = 0.0f;
#pragma unroll
    for (int it = 0; it < 24; it++) {
        int i = tid + it * 256;
        int b = i / HH, c = i % HH;    // each (wave,it) is branch-uniform
        size_t base = (size_t)b * VV * HH;
        float v = bias[c];
        if (c < 128) {
            v += ldS(S, base + (size_t)u * HH + 64 + c);
        } else {
            int d = c - 128;
#pragma unroll
            for (int j = 0; j < 8; j++)
                v += vi[j] * ldS(S, base + (size_t)vc[j] * HH + d);
        }
        yv[it] = v;
        psum += v;
    }
    // block reduce (sum)
#pragma unroll
    for (int off = 32; off; off >>= 1) psum += __shfl_down(psum, off, 64);
    if ((tid & 63) == 0) red[tid >> 6] = psum;
    __syncthreads();
    const float mean = (red[0] + red[1] + red[2] + red[3]) * (1.0f / (BB * HH));
    __syncthreads();
    float pvar = 0.0f;
#pragma unroll
    for (int it = 0; it < 24; it++) { float t = yv[it] - mean; pvar += t * t; }
#pragma unroll
    for (int off = 32; off; off >>= 1) pvar += __shfl_down(pvar, off, 64);
    if ((tid & 63) == 0) red[tid >> 6] = pvar;
    __syncthreads();
    const float rstd = rsqrtf((red[0] + red[1] + red[2] + red[3]) * (1.0f / (BB * HH)) + 1e-5f);
    const float ga = gamma[u], be = beta[u];

#pragma unroll
    for (int it = 0; it < 24; it++) {
        int i = tid + it * 256;
        int b = i / HH, c = i % HH;
        size_t row = (size_t)b * VV + u;
        float o = fmaxf(ga * (yv[it] - mean) * rstd + be, 0.0f);
        if constexpr (MODE == 0) {
            xout[row * HH + c] = f2b(o);
        } else {
            float f;
            if constexpr (MODE == 1)
                f = (c < 3) ? feat3[row * 3 + c] : pooled[row * PD + (c - 3)];
            else
                f = featsF[row * HH + c];
            float fn = (f + o) * 0.5f;
            featsF[row * HH + c] = fn;
            featsB[row * HH + c] = f2b(fn);
            if constexpr (MODE == 3) dOut[row * HH + c] = fn;
        }
    }
}

// ---------------------------------------------------------------------------
// coords support: SC[row][3] = feats[row][:] @ W15[192][3] (tiny GEMM)
__global__ __launch_bounds__(256) void k_cgemm(const bf16* __restrict__ F,
                                               const float* __restrict__ W15,
                                               float* __restrict__ SC) {
    __shared__ bf16 fs[128 * HH];
    const size_t m0 = (size_t)blockIdx.x * 128;
    const int tid = threadIdx.x;
    for (int c = tid; c < 128 * HH / 8; c += 256) {
        int row = c / 24, c8 = (c % 24) * 8;
        *(short8*)(&fs[row * HH + c8]) = *(const short8*)(F + (m0 + row) * HH + c8);
    }
    __syncthreads();
    for (int idx = tid; idx < 128 * 3; idx += 256) {
        int row = idx / 3, o = idx % 3;
        float acc = 0.0f;
        for (int k = 0; k < HH; k++)
            acc += b2f(fs[row * HH + k]) * W15[k * 3 + o];
        if (m0 + row < MROWS) SC[(m0 + row) * 3 + o] = acc;
    }
}

// coords: ch0 = SC[:,2]+b15[0]; ch1/2 = sparse-agg of SC[:,0]/SC[:,1] + b15[1/2]
__global__ void k_cagg(const float* __restrict__ SC, const int* __restrict__ degs,
                       const int* __restrict__ cols, const float* __restrict__ invn,
                       const float* __restrict__ b15, float* __restrict__ out) {
    int gid = blockIdx.x * 256 + threadIdx.x;
    if (gid >= MROWS) return;
    int u = gid % VV;
    int b = gid / VV;
    int deg = degs[u];
    float s0 = 0.0f, s1 = 0.0f;
#pragma unroll
    for (int j = 0; j < 8; j++) {
        if (j < deg) {
            int v = cols[u * 8 + j];
            float w = invn[v];
            s0 += w * SC[((size_t)b * VV + v) * 3 + 0];
            s1 += w * SC[((size_t)b * VV + v) * 3 + 1];
        }
    }
    out[(size_t)gid * 3 + 0] = SC[(size_t)gid * 3 + 2] + b15[0];
    out[(size_t)gid * 3 + 1] = s0 + b15[1];
    out[(size_t)gid * 3 + 2] = s1 + b15[2];
}

// ---------------------------------------------------------------------------
extern "C" void kernel_launch(void* const* d_in, const int* in_sizes, int n_in,
                              void* d_out, int out_size, void* d_ws, size_t ws_size,
                              hipStream_t stream) {
    const float* feat   = (const float*)d_in[0];
    const float* pooled = (const float*)d_in[1];
    const float* adj    = (const float*)d_in[2];
    const float* W1     = (const float*)d_in[3];
    const float* b1     = (const float*)d_in[4];
    const float* Wm     = (const float*)d_in[5];
    const float* bm     = (const float*)d_in[6];
    const float* W15    = (const float*)d_in[7];
    const float* b15    = (const float*)d_in[8];
    const float* gamma  = (const float*)d_in[9];
    const float* beta   = (const float*)d_in[10];
    float* outF = (float*)d_out;                    // feats [B,V,192] fp32
    float* outC = outF + (size_t)MROWS * HH;        // coords [B,V,3] fp32

    char* ws = (char*)d_ws;
    size_t off = 0;
    auto alloc = [&](size_t bytes) -> void* {
        void* p = ws + off;
        off = (off + bytes + 255) & ~(size_t)255;
        return p;
    };
    float* featsF = (float*)alloc((size_t)MP * HH * 4);   // residual state fp32
    bf16*  sB     = (bf16*) alloc((size_t)MP * HH * 2);   // support intermediate
    bf16*  xB     = (bf16*) alloc((size_t)MP * HH * 2);   // BN output x
    bf16*  featsB = (bf16*) alloc((size_t)MP * HH * 2);   // residual state bf16
    bf16*  W1t    = (bf16*) alloc((size_t)HH * KP1 * 2);
    bf16*  Wmt    = (bf16*) alloc((size_t)12 * HH * HH * 2);
    float* SC     = (float*)alloc((size_t)MP * 3 * 4);
    int*   degs   = (int*)  alloc(VV * 4);
    int*   colsp  = (int*)  alloc(VV * 8 * 4);
    float* invn   = (float*)alloc(VV * 4);
    (void)ws_size; (void)in_sizes; (void)n_in; (void)out_size;

    k_csr<<<VV, 256, 0, stream>>>(adj, degs, colsp, invn);
    int ntr = (HH * KP1 + 12 * HH * HH + 255) / 256;
    k_trans<<<ntr, 256, 0, stream>>>(W1, Wm, W1t, Wmt);

    // layer 1: gc1 (K=992 padded), A read directly from fp32 inputs.
    k_gemm1<<<NBLK, 256, 0, stream>>>(feat, pooled, W1t, featsB);
    k_bn<0><<<VV, 256, 0, stream>>>(featsB, degs, colsp, invn, b1,
                                    gamma + 0 * VV, beta + 0 * VV,
                                    nullptr, nullptr, nullptr, nullptr, xB, nullptr);
    // layer 2: gc2 + residual init  feats = (full[:, :192] + x)/2
    k_gemm<<<NBLK, 256, 0, stream>>>(xB, Wmt, sB);
    k_bn<1><<<VV, 256, 0, stream>>>(sB, degs, colsp, invn, bm,
                                    gamma + 1 * VV, beta + 1 * VV,
                                    feat, pooled, featsF, featsB, nullptr, nullptr);
    // five residual pairs
    for (int i = 0; i < 5; i++) {
        int la = 2 * i + 1, lb = 2 * i + 2;
        k_gemm<<<NBLK, 256, 0, stream>>>(featsB, Wmt + (size_t)la * HH * HH, sB);
        k_bn<0><<<VV, 256, 0, stream>>>(sB, degs, colsp, invn, bm + la * HH,
                                        gamma + (size_t)(la + 1) * VV, beta + (size_t)(la + 1) * VV,
                                        nullptr, nullptr, nullptr, nullptr, xB, nullptr);
        k_gemm<<<NBLK, 256, 0, stream>>>(xB, Wmt + (size_t)lb * HH * HH, sB);
        k_bn<2><<<VV, 256, 0, stream>>>(sB, degs, colsp, invn, bm + lb * HH,
                                        gamma + (size_t)(lb + 1) * VV, beta + (size_t)(lb + 1) * VV,
                                        nullptr, nullptr, featsF, featsB, nullptr, nullptr);
    }
    // gc13 + final residual (also writes feats to d_out, fp32)
    k_gemm<<<NBLK, 256, 0, stream>>>(featsB, Wmt + (size_t)11 * HH * HH, sB);
    k_bn<3><<<VV, 256, 0, stream>>>(sB, degs, colsp, invn, bm + 11 * HH,
                                    gamma + (size_t)12 * VV, beta + (size_t)12 * VV,
                                    nullptr, nullptr, featsF, featsB, nullptr, outF);
    // coords head
    k_cgemm<<<NBLK, 256, 0, stream>>>(featsB, W15, SC);
    k_cagg<<<(MROWS + 255) / 256, 256, 0, stream>>>(SC, degs, colsp, invn, b15, outC);
}

// Round 3
// 1546.724 us; speedup vs baseline: 1.0840x; 1.0022x over previous
//
#include <hip/hip_runtime.h>
#include <hip/hip_bf16.h>

// Problem constants
#define BB 32
#define VV 2562
#define HH 192
#define CIN_ 966
#define KP1B 1056          // 966 padded to 11*96 (zero-filled tail) for gemm1
#define PD 963
#define MROWS (BB * VV)    // 81984
#define MP 82048           // 641 * 128 (row-padded M)
#define NBLK 641

typedef __attribute__((ext_vector_type(8))) short short8;
typedef __attribute__((ext_vector_type(4))) float floatx4;
using bf16 = __hip_bfloat16;

static __device__ __forceinline__ float b2f(bf16 x) { return __bfloat162float(x); }
static __device__ __forceinline__ bf16  f2b(float x) { return __float2bfloat16(x); }
static __device__ __forceinline__ float ldS(const float* p, size_t i) { return p[i]; }
static __device__ __forceinline__ float ldS(const bf16*  p, size_t i) { return b2f(p[i]); }

// ---------------------------------------------------------------------------
// CSR build: adj is dense [V,V] 0/1 fp32 with self loops, degree <= 7.
__global__ void k_csr(const float* __restrict__ adj, int* __restrict__ degs,
                      int* __restrict__ cols, float* __restrict__ invn) {
    int u = blockIdx.x;
    __shared__ int cnt;
    if (threadIdx.x == 0) cnt = 0;
    __syncthreads();
    for (int j = threadIdx.x; j < VV; j += blockDim.x) {
        if (adj[(size_t)u * VV + j] != 0.0f) {
            int p = atomicAdd(&cnt, 1);
            if (p < 8) cols[u * 8 + p] = j;
        }
    }
    __syncthreads();
    if (threadIdx.x == 0) {
        degs[u] = (cnt < 8) ? cnt : 8;
        invn[u] = (cnt > 0) ? (1.0f / (float)cnt) : 0.0f;  // guard: no inf
    }
}

// ---------------------------------------------------------------------------
// Weight prep (fp32 -> bf16, transposed): W1t[n][k] (k padded to 1056, zero
// tail), Wmt[l][n][k] from Wm[l][k][n].
__global__ void k_trans(const float* __restrict__ W1, const float* __restrict__ Wm,
                        bf16* __restrict__ W1t, bf16* __restrict__ Wmt) {
    int idx = blockIdx.x * 256 + threadIdx.x;
    const int n1 = HH * KP1B;
    if (idx < n1) {
        int n = idx / KP1B, k = idx % KP1B;
        W1t[idx] = (k < CIN_) ? f2b(W1[(size_t)k * HH + n]) : f2b(0.0f);
    } else {
        int t = idx - n1;
        if (t < 12 * HH * HH) {
            int l = t / (HH * HH);
            int r = t % (HH * HH);
            int n = r / HH, k = r % HH;
            Wmt[t] = f2b(Wm[(size_t)l * HH * HH + (size_t)k * HH + n]);
        }
    }
}

// ---------------------------------------------------------------------------
// GEMM: C[MP x 192](bf16) = A[MP x 192](bf16) * W (bf16, Bt[n][k]).
// Full-K staging: the whole 128x192 A-tile (49 KB) goes to LDS in one shot
// (12 coalesced 16B chunks per thread, 12-deep in flight), then ONE barrier,
// then all 144 MFMAs run barrier-free.  Stride 200 keeps ds_read_b128 at
// <=2-way bank aliasing (free per m136).
__global__ __launch_bounds__(256) void k_gemm(const bf16* __restrict__ A,
                                              const bf16* __restrict__ Bt,
                                              bf16* __restrict__ C) {
    __shared__ bf16 As[128][200];
    const int tid  = threadIdx.x;
    const int wave = tid >> 6, lane = tid & 63;
    const int quad = lane >> 4, l15 = lane & 15;
    const size_t m0 = (size_t)blockIdx.x * 128;

    // Stage: tile is 128*192 contiguous bf16 at A + m0*192.
    short8 st[12];
#pragma unroll
    for (int i = 0; i < 12; i++) {
        int idx = tid + i * 256;
        st[i] = *(const short8*)(A + m0 * HH + (size_t)idx * 8);
    }
#pragma unroll
    for (int i = 0; i < 12; i++) {
        int idx = tid + i * 256;
        int row = idx / 24, col = (idx % 24) * 8;
        *(short8*)(&As[row][col]) = st[i];
    }

    floatx4 acc[8][3];
#pragma unroll
    for (int i = 0; i < 8; i++)
#pragma unroll
        for (int j = 0; j < 3; j++) acc[i][j] = (floatx4){0.f, 0.f, 0.f, 0.f};

    __syncthreads();
#pragma unroll
    for (int k0 = 0; k0 < HH; k0 += 32) {
        short8 bfr[3];
#pragma unroll
        for (int nt = 0; nt < 3; nt++) {
            int n = wave * 48 + nt * 16 + l15;
            bfr[nt] = *(const short8*)(Bt + (size_t)n * HH + k0 + quad * 8);
        }
#pragma unroll
        for (int mt = 0; mt < 8; mt++) {
            short8 afr = *(const short8*)(&As[mt * 16 + l15][k0 + quad * 8]);
#pragma unroll
            for (int nt = 0; nt < 3; nt++)
                acc[mt][nt] = __builtin_amdgcn_mfma_f32_16x16x32_bf16(afr, bfr[nt], acc[mt][nt], 0, 0, 0);
        }
    }
    // Epilogue: D row = quad*4 + r, col = l15 (m89-verified C/D layout)
#pragma unroll
    for (int mt = 0; mt < 8; mt++) {
#pragma unroll
        for (int nt = 0; nt < 3; nt++) {
            int n = wave * 48 + nt * 16 + l15;
#pragma unroll
            for (int r = 0; r < 4; r++) {
                size_t row = m0 + mt * 16 + quad * 4 + r;
                C[row * HH + n] = f2b(acc[mt][nt][r]);
            }
        }
    }
}

// ---------------------------------------------------------------------------
// GEMM layer 1: A is the virtual concat(features, pooled) read directly from
// fp32 inputs, converted to bf16 during staging.  K = 1056 (11 chunks of 96,
// zero tail).  Rows >= MROWS clamp to row 0 (outputs land in padded C rows
// that are never read).  BK=96: 11 barrier-pairs instead of 31.
__global__ __launch_bounds__(256) void k_gemm1(const float* __restrict__ feat,
                                               const float* __restrict__ pooled,
                                               const bf16* __restrict__ Bt,
                                               bf16* __restrict__ C) {
    __shared__ bf16 As[128][104];   // stride 104: ~2-way bank aliasing
    const int tid  = threadIdx.x;
    const int wave = tid >> 6, lane = tid & 63;
    const int quad = lane >> 4, l15 = lane & 15;
    const size_t m0 = (size_t)blockIdx.x * 128;

    floatx4 acc[8][3];
#pragma unroll
    for (int i = 0; i < 8; i++)
#pragma unroll
        for (int j = 0; j < 3; j++) acc[i][j] = (floatx4){0.f, 0.f, 0.f, 0.f};

    for (int kb = 0; kb < KP1B; kb += 96) {
        __syncthreads();
        // stage 128 rows x 96 cols: 1536 chunks of 8, 6 per thread
#pragma unroll
        for (int i = 0; i < 6; i++) {
            int idx = tid + i * 256;
            int rowl = idx / 12, colc = (idx % 12) * 8;
            size_t row = m0 + rowl;
            size_t rr  = (row < MROWS) ? row : 0;   // clamp: padded rows unused
            int c0 = kb + colc;
            union { bf16 hh[8]; short8 v; } t;
            if (c0 >= 3 && c0 + 8 <= CIN_) {
                const float* p = pooled + rr * (size_t)PD + (c0 - 3);
#pragma unroll
                for (int j = 0; j < 8; j++) t.hh[j] = f2b(p[j]);
            } else {
#pragma unroll
                for (int j = 0; j < 8; j++) {
                    int c = c0 + j;
                    float v;
                    if (c < 3)          v = feat[rr * 3 + c];
                    else if (c < CIN_)  v = pooled[rr * (size_t)PD + (c - 3)];
                    else                v = 0.0f;
                    t.hh[j] = f2b(v);
                }
            }
            *(short8*)(&As[rowl][colc]) = t.v;
        }
        __syncthreads();
#pragma unroll
        for (int k0 = 0; k0 < 96; k0 += 32) {
            short8 bfr[3];
#pragma unroll
            for (int nt = 0; nt < 3; nt++) {
                int n = wave * 48 + nt * 16 + l15;
                bfr[nt] = *(const short8*)(Bt + (size_t)n * KP1B + kb + k0 + quad * 8);
            }
#pragma unroll
            for (int mt = 0; mt < 8; mt++) {
                short8 afr = *(const short8*)(&As[mt * 16 + l15][k0 + quad * 8]);
#pragma unroll
                for (int nt = 0; nt < 3; nt++)
                    acc[mt][nt] = __builtin_amdgcn_mfma_f32_16x16x32_bf16(afr, bfr[nt], acc[mt][nt], 0, 0, 0);
            }
        }
    }
#pragma unroll
    for (int mt = 0; mt < 8; mt++) {
#pragma unroll
        for (int nt = 0; nt < 3; nt++) {
            int n = wave * 48 + nt * 16 + l15;
#pragma unroll
            for (int r = 0; r < 4; r++) {
                size_t row = m0 + mt * 16 + quad * 4 + r;
                C[row * HH + n] = f2b(acc[mt][nt][r]);
            }
        }
    }
}

// ---------------------------------------------------------------------------
// Fused: sparse-aggregate + concat-reorder + bias  ->  BN(per-vertex over B,C)
// -> relu -> (store x | residual update).  One block per vertex u.
// MODE 0: write x (bf16) only.
// MODE 1: feats = (full[:, :192] + x)/2  (reads features/pooled fp32).
// MODE 2: feats = (feats + x)/2.
// MODE 3: MODE 2 + write feats to d_out (fp32).
template <int MODE>
__global__ __launch_bounds__(256) void k_bn(const bf16* __restrict__ S,
                                            const int* __restrict__ degs, const int* __restrict__ cols,
                                            const float* __restrict__ invn,
                                            const float* __restrict__ bias,
                                            const float* __restrict__ gamma, const float* __restrict__ beta,
                                            const float* __restrict__ feat3, const float* __restrict__ pooled,
                                            float* __restrict__ featsF, bf16* __restrict__ featsB,
                                            bf16* __restrict__ xout, float* __restrict__ dOut) {
    const int u = blockIdx.x;
    const int tid = threadIdx.x;
    __shared__ float red[4];

    const int deg = degs[u];
    int vc[8]; float vi[8];
#pragma unroll
    for (int j = 0; j < 8; j++) {
        if (j < deg) { vc[j] = cols[u * 8 + j]; vi[j] = invn[vc[j]]; }
        else         { vc[j] = 0;               vi[j] = 0.0f; }      // 0 * finite = 0
    }

    float yv[24];
    float psum = 0.0f;
#pragma unroll
    for (int it = 0; it < 24; it++) {
        int i = tid + it * 256;
        int b = i / HH, c = i % HH;    // each (wave,it) is branch-uniform
        size_t base = (size_t)b * VV * HH;
        float v = bias[c];
        if (c < 128) {
            v += ldS(S, base + (size_t)u * HH + 64 + c);
        } else {
            int d = c - 128;
#pragma unroll
            for (int j = 0; j < 8; j++)
                v += vi[j] * ldS(S, base + (size_t)vc[j] * HH + d);
        }
        yv[it] = v;
        psum += v;
    }
    // block reduce (sum)
#pragma unroll
    for (int off = 32; off; off >>= 1) psum += __shfl_down(psum, off, 64);
    if ((tid & 63) == 0) red[tid >> 6] = psum;
    __syncthreads();
    const float mean = (red[0] + red[1] + red[2] + red[3]) * (1.0f / (BB * HH));
    __syncthreads();
    float pvar = 0.0f;
#pragma unroll
    for (int it = 0; it < 24; it++) { float t = yv[it] - mean; pvar += t * t; }
#pragma unroll
    for (int off = 32; off; off >>= 1) pvar += __shfl_down(pvar, off, 64);
    if ((tid & 63) == 0) red[tid >> 6] = pvar;
    __syncthreads();
    const float rstd = rsqrtf((red[0] + red[1] + red[2] + red[3]) * (1.0f / (BB * HH)) + 1e-5f);
    const float ga = gamma[u], be = beta[u];

#pragma unroll
    for (int it = 0; it < 24; it++) {
        int i = tid + it * 256;
        int b = i / HH, c = i % HH;
        size_t row = (size_t)b * VV + u;
        float o = fmaxf(ga * (yv[it] - mean) * rstd + be, 0.0f);
        if constexpr (MODE == 0) {
            xout[row * HH + c] = f2b(o);
        } else {
            float f;
            if constexpr (MODE == 1)
                f = (c < 3) ? feat3[row * 3 + c] : pooled[row * PD + (c - 3)];
            else
                f = featsF[row * HH + c];
            float fn = (f + o) * 0.5f;
            featsF[row * HH + c] = fn;
            featsB[row * HH + c] = f2b(fn);
            if constexpr (MODE == 3) dOut[row * HH + c] = fn;
        }
    }
}

// ---------------------------------------------------------------------------
// coords support: SC[row][3] = feats[row][:] @ W15[192][3] (tiny GEMM)
__global__ __launch_bounds__(256) void k_cgemm(const bf16* __restrict__ F,
                                               const float* __restrict__ W15,
                                               float* __restrict__ SC) {
    __shared__ bf16 fs[128 * HH];
    const size_t m0 = (size_t)blockIdx.x * 128;
    const int tid = threadIdx.x;
    for (int c = tid; c < 128 * HH / 8; c += 256) {
        int row = c / 24, c8 = (c % 24) * 8;
        *(short8*)(&fs[row * HH + c8]) = *(const short8*)(F + (m0 + row) * HH + c8);
    }
    __syncthreads();
    for (int idx = tid; idx < 128 * 3; idx += 256) {
        int row = idx / 3, o = idx % 3;
        float acc = 0.0f;
        for (int k = 0; k < HH; k++)
            acc += b2f(fs[row * HH + k]) * W15[k * 3 + o];
        if (m0 + row < MROWS) SC[(m0 + row) * 3 + o] = acc;
    }
}

// coords: ch0 = SC[:,2]+b15[0]; ch1/2 = sparse-agg of SC[:,0]/SC[:,1] + b15[1/2]
__global__ void k_cagg(const float* __restrict__ SC, const int* __restrict__ degs,
                       const int* __restrict__ cols, const float* __restrict__ invn,
                       const float* __restrict__ b15, float* __restrict__ out) {
    int gid = blockIdx.x * 256 + threadIdx.x;
    if (gid >= MROWS) return;
    int u = gid % VV;
    int b = gid / VV;
    int deg = degs[u];
    float s0 = 0.0f, s1 = 0.0f;
#pragma unroll
    for (int j = 0; j < 8; j++) {
        if (j < deg) {
            int v = cols[u * 8 + j];
            float w = invn[v];
            s0 += w * SC[((size_t)b * VV + v) * 3 + 0];
            s1 += w * SC[((size_t)b * VV + v) * 3 + 1];
        }
    }
    out[(size_t)gid * 3 + 0] = SC[(size_t)gid * 3 + 2] + b15[0];
    out[(size_t)gid * 3 + 1] = s0 + b15[1];
    out[(size_t)gid * 3 + 2] = s1 + b15[2];
}

// ---------------------------------------------------------------------------
extern "C" void kernel_launch(void* const* d_in, const int* in_sizes, int n_in,
                              void* d_out, int out_size, void* d_ws, size_t ws_size,
                              hipStream_t stream) {
    const float* feat   = (const float*)d_in[0];
    const float* pooled = (const float*)d_in[1];
    const float* adj    = (const float*)d_in[2];
    const float* W1     = (const float*)d_in[3];
    const float* b1     = (const float*)d_in[4];
    const float* Wm     = (const float*)d_in[5];
    const float* bm     = (const float*)d_in[6];
    const float* W15    = (const float*)d_in[7];
    const float* b15    = (const float*)d_in[8];
    const float* gamma  = (const float*)d_in[9];
    const float* beta   = (const float*)d_in[10];
    float* outF = (float*)d_out;                    // feats [B,V,192] fp32
    float* outC = outF + (size_t)MROWS * HH;        // coords [B,V,3] fp32

    char* ws = (char*)d_ws;
    size_t off = 0;
    auto alloc = [&](size_t bytes) -> void* {
        void* p = ws + off;
        off = (off + bytes + 255) & ~(size_t)255;
        return p;
    };
    float* featsF = (float*)alloc((size_t)MP * HH * 4);   // residual state fp32
    bf16*  sB     = (bf16*) alloc((size_t)MP * HH * 2);   // support intermediate
    bf16*  xB     = (bf16*) alloc((size_t)MP * HH * 2);   // BN output x
    bf16*  featsB = (bf16*) alloc((size_t)MP * HH * 2);   // residual state bf16
    bf16*  W1t    = (bf16*) alloc((size_t)HH * KP1B * 2);
    bf16*  Wmt    = (bf16*) alloc((size_t)12 * HH * HH * 2);
    float* SC     = (float*)alloc((size_t)MP * 3 * 4);
    int*   degs   = (int*)  alloc(VV * 4);
    int*   colsp  = (int*)  alloc(VV * 8 * 4);
    float* invn   = (float*)alloc(VV * 4);
    (void)ws_size; (void)in_sizes; (void)n_in; (void)out_size;

    k_csr<<<VV, 256, 0, stream>>>(adj, degs, colsp, invn);
    int ntr = (HH * KP1B + 12 * HH * HH + 255) / 256;
    k_trans<<<ntr, 256, 0, stream>>>(W1, Wm, W1t, Wmt);

    // layer 1: gc1 (K=1056 padded), A read directly from fp32 inputs.
    k_gemm1<<<NBLK, 256, 0, stream>>>(feat, pooled, W1t, featsB);
    k_bn<0><<<VV, 256, 0, stream>>>(featsB, degs, colsp, invn, b1,
                                    gamma + 0 * VV, beta + 0 * VV,
                                    nullptr, nullptr, nullptr, nullptr, xB, nullptr);
    // layer 2: gc2 + residual init  feats = (full[:, :192] + x)/2
    k_gemm<<<NBLK, 256, 0, stream>>>(xB, Wmt, sB);
    k_bn<1><<<VV, 256, 0, stream>>>(sB, degs, colsp, invn, bm,
                                    gamma + 1 * VV, beta + 1 * VV,
                                    feat, pooled, featsF, featsB, nullptr, nullptr);
    // five residual pairs
    for (int i = 0; i < 5; i++) {
        int la = 2 * i + 1, lb = 2 * i + 2;
        k_gemm<<<NBLK, 256, 0, stream>>>(featsB, Wmt + (size_t)la * HH * HH, sB);
        k_bn<0><<<VV, 256, 0, stream>>>(sB, degs, colsp, invn, bm + la * HH,
                                        gamma + (size_t)(la + 1) * VV, beta + (size_t)(la + 1) * VV,
                                        nullptr, nullptr, nullptr, nullptr, xB, nullptr);
        k_gemm<<<NBLK, 256, 0, stream>>>(xB, Wmt + (size_t)lb * HH * HH, sB);
        k_bn<2><<<VV, 256, 0, stream>>>(sB, degs, colsp, invn, bm + lb * HH,
                                        gamma + (size_t)(lb + 1) * VV, beta + (size_t)(lb + 1) * VV,
                                        nullptr, nullptr, featsF, featsB, nullptr, nullptr);
    }
    // gc13 + final residual (also writes feats to d_out, fp32)
    k_gemm<<<NBLK, 256, 0, stream>>>(featsB, Wmt + (size_t)11 * HH * HH, sB);
    k_bn<3><<<VV, 256, 0, stream>>>(sB, degs, colsp, invn, bm + 11 * HH,
                                    gamma + (size_t)12 * VV, beta + (size_t)12 * VV,
                                    nullptr, nullptr, featsF, featsB, nullptr, outF);
    // coords head
    k_cgemm<<<NBLK, 256, 0, stream>>>(featsB, W15, SC);
    k_cagg<<<(MROWS + 255) / 256, 256, 0, stream>>>(SC, degs, colsp, invn, b15, outC);
}

// Round 5
// 1270.423 us; speedup vs baseline: 1.3198x; 1.2175x over previous
//
#include <hip/hip_runtime.h>
#include <hip/hip_bf16.h>

// Problem constants
#define BB 32
#define VV 2562
#define HH 192
#define CIN_ 966
#define KP1B 1056          // 966 padded to 11*96; K-permuted: pooled[0..962], feat[963..965], zeros
#define PD 963
#define MROWS (BB * VV)    // 81984 = 1281 * 64 exactly
#define MP 82048           // alloc padding only
#define GR64 1281          // 64-row tiles

typedef __attribute__((ext_vector_type(8))) short short8;
typedef __attribute__((ext_vector_type(4))) float floatx4;
using bf16 = __hip_bfloat16;

static __device__ __forceinline__ float b2f(bf16 x) { return __bfloat162float(x); }
static __device__ __forceinline__ bf16  f2b(float x) { return __float2bfloat16(x); }

// ---------------------------------------------------------------------------
// CSR build: adj is dense [V,V] 0/1 fp32 with self loops, degree <= 7.
__global__ void k_csr(const float* __restrict__ adj, int* __restrict__ degs,
                      int* __restrict__ cols, float* __restrict__ invn) {
    int u = blockIdx.x;
    __shared__ int cnt;
    if (threadIdx.x == 0) cnt = 0;
    __syncthreads();
    for (int j = threadIdx.x; j < VV; j += blockDim.x) {
        if (adj[(size_t)u * VV + j] != 0.0f) {
            int p = atomicAdd(&cnt, 1);
            if (p < 8) cols[u * 8 + p] = j;
        }
    }
    __syncthreads();
    if (threadIdx.x == 0) {
        degs[u] = (cnt < 8) ? cnt : 8;
        invn[u] = (cnt > 0) ? (1.0f / (float)cnt) : 0.0f;  // guard: no inf
    }
}

// ---------------------------------------------------------------------------
// Weight prep (fp32 -> bf16, transposed).  W1t uses the K-PERMUTED layout:
// k<963 -> W1 row k+3 (pooled cols), 963..965 -> W1 rows 0..2 (feat cols),
// >=966 -> 0.  Wmt[l][n][k] from Wm[l][k][n].
__global__ void k_trans(const float* __restrict__ W1, const float* __restrict__ Wm,
                        bf16* __restrict__ W1t, bf16* __restrict__ Wmt) {
    int idx = blockIdx.x * 256 + threadIdx.x;
    const int n1 = HH * KP1B;
    if (idx < n1) {
        int n = idx / KP1B, k = idx % KP1B;
        float w = 0.0f;
        if (k < 963)      w = W1[(size_t)(k + 3) * HH + n];
        else if (k < 966) w = W1[(size_t)(k - 963) * HH + n];
        W1t[idx] = f2b(w);
    } else {
        int t = idx - n1;
        if (t < 12 * HH * HH) {
            int l = t / (HH * HH);
            int r = t % (HH * HH);
            int n = r / HH, k = r % HH;
            Wmt[t] = f2b(Wm[(size_t)l * HH * HH + (size_t)k * HH + n]);
        }
    }
}

// ---------------------------------------------------------------------------
// Mid GEMM: C[M x 192](bf16) = A[M x 192](bf16) * W (bf16, Bt[n][k]).
// 64-row tiles (grid 1281, ~5 blocks/CU), full-K staging, one barrier.
// LDS stride 200 keeps ds_read_b128 at <=2-way bank aliasing (free, m136).
__global__ __launch_bounds__(256, 4) void k_gemm(const bf16* __restrict__ A,
                                                 const bf16* __restrict__ Bt,
                                                 bf16* __restrict__ C) {
    __shared__ bf16 As[64][200];
    const int tid  = threadIdx.x;
    const int wave = tid >> 6, lane = tid & 63;
    const int quad = lane >> 4, l15 = lane & 15;
    const size_t m0 = (size_t)blockIdx.x * 64;

    short8 st[6];
#pragma unroll
    for (int i = 0; i < 6; i++)
        st[i] = *(const short8*)(A + m0 * HH + ((size_t)tid + i * 256) * 8);
#pragma unroll
    for (int i = 0; i < 6; i++) {
        int idx = tid + i * 256;
        *(short8*)(&As[idx / 24][(idx % 24) * 8]) = st[i];
    }

    floatx4 acc[4][3];
#pragma unroll
    for (int i = 0; i < 4; i++)
#pragma unroll
        for (int j = 0; j < 3; j++) acc[i][j] = (floatx4){0.f, 0.f, 0.f, 0.f};

    __syncthreads();
#pragma unroll
    for (int k0 = 0; k0 < HH; k0 += 32) {
        short8 bfr[3];
#pragma unroll
        for (int nt = 0; nt < 3; nt++) {
            int n = wave * 48 + nt * 16 + l15;
            bfr[nt] = *(const short8*)(Bt + (size_t)n * HH + k0 + quad * 8);
        }
#pragma unroll
        for (int mt = 0; mt < 4; mt++) {
            short8 afr = *(const short8*)(&As[mt * 16 + l15][k0 + quad * 8]);
#pragma unroll
            for (int nt = 0; nt < 3; nt++)
                acc[mt][nt] = __builtin_amdgcn_mfma_f32_16x16x32_bf16(afr, bfr[nt], acc[mt][nt], 0, 0, 0);
        }
    }
    // Epilogue: D row = quad*4 + r, col = l15 (m89-verified C/D layout)
#pragma unroll
    for (int mt = 0; mt < 4; mt++) {
#pragma unroll
        for (int nt = 0; nt < 3; nt++) {
            int n = wave * 48 + nt * 16 + l15;
#pragma unroll
            for (int r = 0; r < 4; r++) {
                size_t row = m0 + mt * 16 + quad * 4 + r;
                C[row * HH + n] = f2b(acc[mt][nt][r]);
            }
        }
    }
}

// ---------------------------------------------------------------------------
// GEMM layer 1 (K-permuted): A[row][k] = pooled[row][k] for k<963, feat for
// 963..965, zero tail.  10 of 11 K-steps are pure-pooled: loads batched
// register-first (24 independent fp32 loads issued before any convert).
__global__ __launch_bounds__(256, 4) void k_gemm1(const float* __restrict__ feat,
                                                  const float* __restrict__ pooled,
                                                  const bf16* __restrict__ Bt,
                                                  bf16* __restrict__ C) {
    __shared__ bf16 As[64][104];   // stride 104: ~2-way bank aliasing
    const int tid  = threadIdx.x;
    const int wave = tid >> 6, lane = tid & 63;
    const int quad = lane >> 4, l15 = lane & 15;
    const size_t m0 = (size_t)blockIdx.x * 64;

    floatx4 acc[4][3];
#pragma unroll
    for (int i = 0; i < 4; i++)
#pragma unroll
        for (int j = 0; j < 3; j++) acc[i][j] = (floatx4){0.f, 0.f, 0.f, 0.f};

    for (int kb = 0; kb < KP1B; kb += 96) {
        __syncthreads();
        if (kb < 960) {
            // fast path: 64 rows x 96 pooled cols, 3 chunks/thread, reg-first
            float v[3][8];
#pragma unroll
            for (int i = 0; i < 3; i++) {
                int idx = tid + i * 256;
                int rowl = idx / 12, colc = (idx % 12) * 8;
                const float* p = pooled + (m0 + rowl) * (size_t)PD + kb + colc;
#pragma unroll
                for (int j = 0; j < 8; j++) v[i][j] = p[j];
            }
#pragma unroll
            for (int i = 0; i < 3; i++) {
                int idx = tid + i * 256;
                int rowl = idx / 12, colc = (idx % 12) * 8;
                union { bf16 h[8]; short8 s; } t;
#pragma unroll
                for (int j = 0; j < 8; j++) t.h[j] = f2b(v[i][j]);
                *(short8*)(&As[rowl][colc]) = t.s;
            }
        } else {
            // kb == 960: cols 960..962 pooled, 963..965 feat, rest zero
#pragma unroll
            for (int i = 0; i < 3; i++) {
                int idx = tid + i * 256;
                int rowl = idx / 12, colc = (idx % 12) * 8;
                int c0 = kb + colc;
                union { bf16 h[8]; short8 s; } t;
#pragma unroll
                for (int j = 0; j < 8; j++) {
                    int c = c0 + j;
                    float vv = 0.0f;
                    if (c < 963)      vv = pooled[(m0 + rowl) * (size_t)PD + c];
                    else if (c < 966) vv = feat[(m0 + rowl) * 3 + (c - 963)];
                    t.h[j] = f2b(vv);
                }
                *(short8*)(&As[rowl][colc]) = t.s;
            }
        }
        __syncthreads();
#pragma unroll
        for (int k0 = 0; k0 < 96; k0 += 32) {
            short8 bfr[3];
#pragma unroll
            for (int nt = 0; nt < 3; nt++) {
                int n = wave * 48 + nt * 16 + l15;
                bfr[nt] = *(const short8*)(Bt + (size_t)n * KP1B + kb + k0 + quad * 8);
            }
#pragma unroll
            for (int mt = 0; mt < 4; mt++) {
                short8 afr = *(const short8*)(&As[mt * 16 + l15][k0 + quad * 8]);
#pragma unroll
                for (int nt = 0; nt < 3; nt++)
                    acc[mt][nt] = __builtin_amdgcn_mfma_f32_16x16x32_bf16(afr, bfr[nt], acc[mt][nt], 0, 0, 0);
            }
        }
    }
#pragma unroll
    for (int mt = 0; mt < 4; mt++) {
#pragma unroll
        for (int nt = 0; nt < 3; nt++) {
            int n = wave * 48 + nt * 16 + l15;
#pragma unroll
            for (int r = 0; r < 4; r++) {
                size_t row = m0 + mt * 16 + quad * 4 + r;
                C[row * HH + n] = f2b(acc[mt][nt][r]);
            }
        }
    }
}

// ---------------------------------------------------------------------------
// Fused: sparse-aggregate + concat-reorder + bias -> BN(per-vertex over B,C)
// -> relu -> (store x | residual update).  One block per vertex u.
// Vectorized: each thread owns 3 chunks of 8 consecutive channels (short8 /
// floatx4 loads and stores throughout).
// MODE 0: write x (bf16).  MODE 1: feats=(full[:,:192]+x)/2.
// MODE 2: feats=(feats+x)/2.  MODE 3: MODE 2 + write feats to d_out.
template <int MODE>
__global__ __launch_bounds__(256) void k_bn(const bf16* __restrict__ S,
                                            const int* __restrict__ degs, const int* __restrict__ cols,
                                            const float* __restrict__ invn,
                                            const float* __restrict__ bias,
                                            const float* __restrict__ gamma, const float* __restrict__ beta,
                                            const float* __restrict__ feat3, const float* __restrict__ pooled,
                                            float* __restrict__ featsF, bf16* __restrict__ featsB,
                                            bf16* __restrict__ xout, float* __restrict__ dOut) {
    const int u = blockIdx.x;
    const int tid = threadIdx.x;
    __shared__ float red[4];

    const int deg = degs[u];
    int vc[8]; float vi[8];
#pragma unroll
    for (int j = 0; j < 8; j++) {
        if (j < deg) { vc[j] = cols[u * 8 + j]; vi[j] = invn[vc[j]]; }
        else         { vc[j] = 0;               vi[j] = 0.0f; }      // 0 * finite = 0
    }

    float yv[3][8];
    float psum = 0.0f;
#pragma unroll
    for (int i = 0; i < 3; i++) {
        int id = tid + i * 256;
        int b = id / 24, c8 = (id % 24) * 8;
        size_t base = (size_t)b * VV * HH;
        floatx4 bl = *(const floatx4*)(bias + c8);
        floatx4 bh = *(const floatx4*)(bias + c8 + 4);
        float v[8] = {bl[0], bl[1], bl[2], bl[3], bh[0], bh[1], bh[2], bh[3]};
        if (c8 < 128) {
            union { bf16 h[8]; short8 s; } t;
            t.s = *(const short8*)(S + base + (size_t)u * HH + 64 + c8);
#pragma unroll
            for (int j = 0; j < 8; j++) v[j] += b2f(t.h[j]);
        } else {
            int d8 = c8 - 128;
#pragma unroll
            for (int jn = 0; jn < 8; jn++) {
                union { bf16 h[8]; short8 s; } t;
                t.s = *(const short8*)(S + base + (size_t)vc[jn] * HH + d8);
#pragma unroll
                for (int j = 0; j < 8; j++) v[j] += vi[jn] * b2f(t.h[j]);
            }
        }
#pragma unroll
        for (int j = 0; j < 8; j++) { yv[i][j] = v[j]; psum += v[j]; }
    }
    // block reduce (sum)
#pragma unroll
    for (int off = 32; off; off >>= 1) psum += __shfl_down(psum, off, 64);
    if ((tid & 63) == 0) red[tid >> 6] = psum;
    __syncthreads();
    const float mean = (red[0] + red[1] + red[2] + red[3]) * (1.0f / (BB * HH));
    __syncthreads();
    float pvar = 0.0f;
#pragma unroll
    for (int i = 0; i < 3; i++)
#pragma unroll
        for (int j = 0; j < 8; j++) { float t = yv[i][j] - mean; pvar += t * t; }
#pragma unroll
    for (int off = 32; off; off >>= 1) pvar += __shfl_down(pvar, off, 64);
    if ((tid & 63) == 0) red[tid >> 6] = pvar;
    __syncthreads();
    const float rstd = rsqrtf((red[0] + red[1] + red[2] + red[3]) * (1.0f / (BB * HH)) + 1e-5f);
    const float ga = gamma[u], be = beta[u];

#pragma unroll
    for (int i = 0; i < 3; i++) {
        int id = tid + i * 256;
        int b = id / 24, c8 = (id % 24) * 8;
        size_t row = (size_t)b * VV + u;
        float o[8];
#pragma unroll
        for (int j = 0; j < 8; j++)
            o[j] = fmaxf(ga * (yv[i][j] - mean) * rstd + be, 0.0f);
        if constexpr (MODE == 0) {
            union { bf16 h[8]; short8 s; } t;
#pragma unroll
            for (int j = 0; j < 8; j++) t.h[j] = f2b(o[j]);
            *(short8*)(xout + row * HH + c8) = t.s;
        } else {
            float f[8];
            if constexpr (MODE == 1) {
                if (c8 == 0) {
                    f[0] = feat3[row * 3 + 0];
                    f[1] = feat3[row * 3 + 1];
                    f[2] = feat3[row * 3 + 2];
#pragma unroll
                    for (int j = 3; j < 8; j++) f[j] = pooled[row * (size_t)PD + (j - 3)];
                } else {
#pragma unroll
                    for (int j = 0; j < 8; j++) f[j] = pooled[row * (size_t)PD + (c8 + j - 3)];
                }
            } else {
                floatx4 f0 = *(const floatx4*)(featsF + row * HH + c8);
                floatx4 f1 = *(const floatx4*)(featsF + row * HH + c8 + 4);
                f[0] = f0[0]; f[1] = f0[1]; f[2] = f0[2]; f[3] = f0[3];
                f[4] = f1[0]; f[5] = f1[1]; f[6] = f1[2]; f[7] = f1[3];
            }
            float fn[8];
#pragma unroll
            for (int j = 0; j < 8; j++) fn[j] = (f[j] + o[j]) * 0.5f;
            *(floatx4*)(featsF + row * HH + c8)     = (floatx4){fn[0], fn[1], fn[2], fn[3]};
            *(floatx4*)(featsF + row * HH + c8 + 4) = (floatx4){fn[4], fn[5], fn[6], fn[7]};
            union { bf16 h[8]; short8 s; } t;
#pragma unroll
            for (int j = 0; j < 8; j++) t.h[j] = f2b(fn[j]);
            *(short8*)(featsB + row * HH + c8) = t.s;
            if constexpr (MODE == 3) {
                *(floatx4*)(dOut + row * HH + c8)     = (floatx4){fn[0], fn[1], fn[2], fn[3]};
                *(floatx4*)(dOut + row * HH + c8 + 4) = (floatx4){fn[4], fn[5], fn[6], fn[7]};
            }
        }
    }
}

// ---------------------------------------------------------------------------
// coords support: SC[row][3] = feats[row][:] @ W15[192][3] (tiny GEMM)
__global__ __launch_bounds__(256) void k_cgemm(const bf16* __restrict__ F,
                                               const float* __restrict__ W15,
                                               float* __restrict__ SC) {
    __shared__ bf16 fs[64 * HH];
    const size_t m0 = (size_t)blockIdx.x * 64;
    const int tid = threadIdx.x;
    for (int c = tid; c < 64 * HH / 8; c += 256) {
        int row = c / 24, c8 = (c % 24) * 8;
        *(short8*)(&fs[row * HH + c8]) = *(const short8*)(F + (m0 + row) * HH + c8);
    }
    __syncthreads();
    for (int idx = tid; idx < 64 * 3; idx += 256) {
        int row = idx / 3, o = idx % 3;
        float acc = 0.0f;
        for (int k = 0; k < HH; k++)
            acc += b2f(fs[row * HH + k]) * W15[k * 3 + o];
        SC[(m0 + row) * 3 + o] = acc;
    }
}

// coords: ch0 = SC[:,2]+b15[0]; ch1/2 = sparse-agg of SC[:,0]/SC[:,1] + b15[1/2]
__global__ void k_cagg(const float* __restrict__ SC, const int* __restrict__ degs,
                       const int* __restrict__ cols, const float* __restrict__ invn,
                       const float* __restrict__ b15, float* __restrict__ out) {
    int gid = blockIdx.x * 256 + threadIdx.x;
    if (gid >= MROWS) return;
    int u = gid % VV;
    int b = gid / VV;
    int deg = degs[u];
    float s0 = 0.0f, s1 = 0.0f;
#pragma unroll
    for (int j = 0; j < 8; j++) {
        if (j < deg) {
            int v = cols[u * 8 + j];
            float w = invn[v];
            s0 += w * SC[((size_t)b * VV + v) * 3 + 0];
            s1 += w * SC[((size_t)b * VV + v) * 3 + 1];
        }
    }
    out[(size_t)gid * 3 + 0] = SC[(size_t)gid * 3 + 2] + b15[0];
    out[(size_t)gid * 3 + 1] = s0 + b15[1];
    out[(size_t)gid * 3 + 2] = s1 + b15[2];
}

// ---------------------------------------------------------------------------
extern "C" void kernel_launch(void* const* d_in, const int* in_sizes, int n_in,
                              void* d_out, int out_size, void* d_ws, size_t ws_size,
                              hipStream_t stream) {
    const float* feat   = (const float*)d_in[0];
    const float* pooled = (const float*)d_in[1];
    const float* adj    = (const float*)d_in[2];
    const float* W1     = (const float*)d_in[3];
    const float* b1     = (const float*)d_in[4];
    const float* Wm     = (const float*)d_in[5];
    const float* bm     = (const float*)d_in[6];
    const float* W15    = (const float*)d_in[7];
    const float* b15    = (const float*)d_in[8];
    const float* gamma  = (const float*)d_in[9];
    const float* beta   = (const float*)d_in[10];
    float* outF = (float*)d_out;                    // feats [B,V,192] fp32
    float* outC = outF + (size_t)MROWS * HH;        // coords [B,V,3] fp32

    char* ws = (char*)d_ws;
    size_t off = 0;
    auto alloc = [&](size_t bytes) -> void* {
        void* p = ws + off;
        off = (off + bytes + 255) & ~(size_t)255;
        return p;
    };
    float* featsF = (float*)alloc((size_t)MP * HH * 4);   // residual state fp32
    bf16*  sB     = (bf16*) alloc((size_t)MP * HH * 2);   // support intermediate
    bf16*  xB     = (bf16*) alloc((size_t)MP * HH * 2);   // BN output x
    bf16*  featsB = (bf16*) alloc((size_t)MP * HH * 2);   // residual state bf16
    bf16*  W1t    = (bf16*) alloc((size_t)HH * KP1B * 2);
    bf16*  Wmt    = (bf16*) alloc((size_t)12 * HH * HH * 2);
    float* SC     = (float*)alloc((size_t)MP * 3 * 4);
    int*   degs   = (int*)  alloc(VV * 4);
    int*   colsp  = (int*)  alloc(VV * 8 * 4);
    float* invn   = (float*)alloc(VV * 4);
    (void)ws_size; (void)in_sizes; (void)n_in; (void)out_size;

    k_csr<<<VV, 256, 0, stream>>>(adj, degs, colsp, invn);
    int ntr = (HH * KP1B + 12 * HH * HH + 255) / 256;
    k_trans<<<ntr, 256, 0, stream>>>(W1, Wm, W1t, Wmt);

    // layer 1: gc1 (K-permuted, K=1056), A read directly from fp32 inputs.
    k_gemm1<<<GR64, 256, 0, stream>>>(feat, pooled, W1t, featsB);
    k_bn<0><<<VV, 256, 0, stream>>>(featsB, degs, colsp, invn, b1,
                                    gamma + 0 * VV, beta + 0 * VV,
                                    nullptr, nullptr, nullptr, nullptr, xB, nullptr);
    // layer 2: gc2 + residual init  feats = (full[:, :192] + x)/2
    k_gemm<<<GR64, 256, 0, stream>>>(xB, Wmt, sB);
    k_bn<1><<<VV, 256, 0, stream>>>(sB, degs, colsp, invn, bm,
                                    gamma + 1 * VV, beta + 1 * VV,
                                    feat, pooled, featsF, featsB, nullptr, nullptr);
    // five residual pairs
    for (int i = 0; i < 5; i++) {
        int la = 2 * i + 1, lb = 2 * i + 2;
        k_gemm<<<GR64, 256, 0, stream>>>(featsB, Wmt + (size_t)la * HH * HH, sB);
        k_bn<0><<<VV, 256, 0, stream>>>(sB, degs, colsp, invn, bm + la * HH,
                                        gamma + (size_t)(la + 1) * VV, beta + (size_t)(la + 1) * VV,
                                        nullptr, nullptr, nullptr, nullptr, xB, nullptr);
        k_gemm<<<GR64, 256, 0, stream>>>(xB, Wmt + (size_t)lb * HH * HH, sB);
        k_bn<2><<<VV, 256, 0, stream>>>(sB, degs, colsp, invn, bm + lb * HH,
                                        gamma + (size_t)(lb + 1) * VV, beta + (size_t)(lb + 1) * VV,
                                        nullptr, nullptr, featsF, featsB, nullptr, nullptr);
    }
    // gc13 + final residual (also writes feats to d_out, fp32)
    k_gemm<<<GR64, 256, 0, stream>>>(featsB, Wmt + (size_t)11 * HH * HH, sB);
    k_bn<3><<<VV, 256, 0, stream>>>(sB, degs, colsp, invn, bm + 11 * HH,
                                    gamma + (size_t)12 * VV, beta + (size_t)12 * VV,
                                    nullptr, nullptr, featsF, featsB, nullptr, outF);
    // coords head
    k_cgemm<<<GR64, 256, 0, stream>>>(featsB, W15, SC);
    k_cagg<<<(MROWS + 255) / 256, 256, 0, stream>>>(SC, degs, colsp, invn, b15, outC);
}

// Round 6
// 1155.068 us; speedup vs baseline: 1.4516x; 1.0999x over previous
//
#include <hip/hip_runtime.h>
#include <hip/hip_bf16.h>

// Problem constants
#define BB 32
#define VV 2562
#define HH 192
#define CIN_ 966
#define KP1B 1056          // 966 padded to 11*96; K-permuted: pooled[0..962], feat[963..965], zeros
#define PD 963
#define MROWS (BB * VV)    // 81984 = 1281 * 64 exactly
#define MP 82048           // alloc padding only
#define GR64 1281          // 64-row tiles

typedef __attribute__((ext_vector_type(8))) short short8;
typedef __attribute__((ext_vector_type(4))) float floatx4;
using bf16 = __hip_bfloat16;

static __device__ __forceinline__ float b2f(bf16 x) { return __bfloat162float(x); }
static __device__ __forceinline__ bf16  f2b(float x) { return __float2bfloat16(x); }

// ---------------------------------------------------------------------------
// CSR build: adj is dense [V,V] 0/1 fp32 with self loops, degree <= 7.
__global__ void k_csr(const float* __restrict__ adj, int* __restrict__ degs,
                      int* __restrict__ cols, float* __restrict__ invn) {
    int u = blockIdx.x;
    __shared__ int cnt;
    if (threadIdx.x == 0) cnt = 0;
    __syncthreads();
    for (int j = threadIdx.x; j < VV; j += blockDim.x) {
        if (adj[(size_t)u * VV + j] != 0.0f) {
            int p = atomicAdd(&cnt, 1);
            if (p < 8) cols[u * 8 + p] = j;
        }
    }
    __syncthreads();
    if (threadIdx.x == 0) {
        degs[u] = (cnt < 8) ? cnt : 8;
        invn[u] = (cnt > 0) ? (1.0f / (float)cnt) : 0.0f;  // guard: no inf
    }
}

// ---------------------------------------------------------------------------
// Weight prep (fp32 -> bf16, transposed).  W1t uses the K-PERMUTED layout:
// k<963 -> W1 row k+3 (pooled cols), 963..965 -> W1 rows 0..2 (feat cols),
// >=966 -> 0.  Wmt[l][n][k] from Wm[l][k][n].
// Tail range: precompute per-neighbor weights vw[u][j] = invn[cols[u][j]]
// (and zero-pad cols beyond degree) so k_bn needs no pointer-chase and no
// degree branch (w=0 annihilates pad lanes).
__global__ void k_trans(const float* __restrict__ W1, const float* __restrict__ Wm,
                        const int* __restrict__ degs, int* __restrict__ cols,
                        const float* __restrict__ invn,
                        bf16* __restrict__ W1t, bf16* __restrict__ Wmt,
                        float* __restrict__ vw) {
    int idx = blockIdx.x * 256 + threadIdx.x;
    const int n1 = HH * KP1B;
    const int n2 = 12 * HH * HH;
    if (idx < n1) {
        int n = idx / KP1B, k = idx % KP1B;
        float w = 0.0f;
        if (k < 963)      w = W1[(size_t)(k + 3) * HH + n];
        else if (k < 966) w = W1[(size_t)(k - 963) * HH + n];
        W1t[idx] = f2b(w);
    } else if (idx < n1 + n2) {
        int t = idx - n1;
        int l = t / (HH * HH);
        int r = t % (HH * HH);
        int n = r / HH, k = r % HH;
        Wmt[t] = f2b(Wm[(size_t)l * HH * HH + (size_t)k * HH + n]);
    } else {
        int t2 = idx - n1 - n2;
        if (t2 < VV * 8) {
            int u = t2 >> 3, j = t2 & 7;
            if (j < degs[u]) {
                vw[t2] = invn[cols[t2]];
            } else {
                cols[t2] = 0;          // safe pad target
                vw[t2] = 0.0f;         // 0 * finite = 0
            }
        }
    }
}

// ---------------------------------------------------------------------------
// Mid GEMM: C[M x 192](bf16) = A[M x 192](bf16) * W (bf16, Bt[n][k]).
// 64-row tiles (grid 1281, ~5 blocks/CU), full-K staging, one barrier.
// LDS stride 200 keeps ds_read_b128 at <=2-way bank aliasing (free, m136).
__global__ __launch_bounds__(256, 4) void k_gemm(const bf16* __restrict__ A,
                                                 const bf16* __restrict__ Bt,
                                                 bf16* __restrict__ C) {
    __shared__ bf16 As[64][200];
    const int tid  = threadIdx.x;
    const int wave = tid >> 6, lane = tid & 63;
    const int quad = lane >> 4, l15 = lane & 15;
    const size_t m0 = (size_t)blockIdx.x * 64;

    short8 st[6];
#pragma unroll
    for (int i = 0; i < 6; i++)
        st[i] = *(const short8*)(A + m0 * HH + ((size_t)tid + i * 256) * 8);
#pragma unroll
    for (int i = 0; i < 6; i++) {
        int idx = tid + i * 256;
        *(short8*)(&As[idx / 24][(idx % 24) * 8]) = st[i];
    }

    floatx4 acc[4][3];
#pragma unroll
    for (int i = 0; i < 4; i++)
#pragma unroll
        for (int j = 0; j < 3; j++) acc[i][j] = (floatx4){0.f, 0.f, 0.f, 0.f};

    __syncthreads();
#pragma unroll
    for (int k0 = 0; k0 < HH; k0 += 32) {
        short8 bfr[3];
#pragma unroll
        for (int nt = 0; nt < 3; nt++) {
            int n = wave * 48 + nt * 16 + l15;
            bfr[nt] = *(const short8*)(Bt + (size_t)n * HH + k0 + quad * 8);
        }
#pragma unroll
        for (int mt = 0; mt < 4; mt++) {
            short8 afr = *(const short8*)(&As[mt * 16 + l15][k0 + quad * 8]);
#pragma unroll
            for (int nt = 0; nt < 3; nt++)
                acc[mt][nt] = __builtin_amdgcn_mfma_f32_16x16x32_bf16(afr, bfr[nt], acc[mt][nt], 0, 0, 0);
        }
    }
    // Epilogue: D row = quad*4 + r, col = l15 (m89-verified C/D layout)
#pragma unroll
    for (int mt = 0; mt < 4; mt++) {
#pragma unroll
        for (int nt = 0; nt < 3; nt++) {
            int n = wave * 48 + nt * 16 + l15;
#pragma unroll
            for (int r = 0; r < 4; r++) {
                size_t row = m0 + mt * 16 + quad * 4 + r;
                C[row * HH + n] = f2b(acc[mt][nt][r]);
            }
        }
    }
}

// ---------------------------------------------------------------------------
// GEMM layer 1 (K-permuted): A[row][k] = pooled[row][k] for k<963, feat for
// 963..965, zero tail.  10 of 11 K-steps are pure-pooled: loads batched
// register-first (24 independent fp32 loads issued before any convert).
__global__ __launch_bounds__(256, 4) void k_gemm1(const float* __restrict__ feat,
                                                  const float* __restrict__ pooled,
                                                  const bf16* __restrict__ Bt,
                                                  bf16* __restrict__ C) {
    __shared__ bf16 As[64][104];   // stride 104: ~2-way bank aliasing
    const int tid  = threadIdx.x;
    const int wave = tid >> 6, lane = tid & 63;
    const int quad = lane >> 4, l15 = lane & 15;
    const size_t m0 = (size_t)blockIdx.x * 64;

    floatx4 acc[4][3];
#pragma unroll
    for (int i = 0; i < 4; i++)
#pragma unroll
        for (int j = 0; j < 3; j++) acc[i][j] = (floatx4){0.f, 0.f, 0.f, 0.f};

    for (int kb = 0; kb < KP1B; kb += 96) {
        __syncthreads();
        if (kb < 960) {
            // fast path: 64 rows x 96 pooled cols, 3 chunks/thread, reg-first
            float v[3][8];
#pragma unroll
            for (int i = 0; i < 3; i++) {
                int idx = tid + i * 256;
                int rowl = idx / 12, colc = (idx % 12) * 8;
                const float* p = pooled + (m0 + rowl) * (size_t)PD + kb + colc;
#pragma unroll
                for (int j = 0; j < 8; j++) v[i][j] = p[j];
            }
#pragma unroll
            for (int i = 0; i < 3; i++) {
                int idx = tid + i * 256;
                int rowl = idx / 12, colc = (idx % 12) * 8;
                union { bf16 h[8]; short8 s; } t;
#pragma unroll
                for (int j = 0; j < 8; j++) t.h[j] = f2b(v[i][j]);
                *(short8*)(&As[rowl][colc]) = t.s;
            }
        } else {
            // kb == 960: cols 960..962 pooled, 963..965 feat, rest zero
#pragma unroll
            for (int i = 0; i < 3; i++) {
                int idx = tid + i * 256;
                int rowl = idx / 12, colc = (idx % 12) * 8;
                int c0 = kb + colc;
                union { bf16 h[8]; short8 s; } t;
#pragma unroll
                for (int j = 0; j < 8; j++) {
                    int c = c0 + j;
                    float vv = 0.0f;
                    if (c < 963)      vv = pooled[(m0 + rowl) * (size_t)PD + c];
                    else if (c < 966) vv = feat[(m0 + rowl) * 3 + (c - 963)];
                    t.h[j] = f2b(vv);
                }
                *(short8*)(&As[rowl][colc]) = t.s;
            }
        }
        __syncthreads();
#pragma unroll
        for (int k0 = 0; k0 < 96; k0 += 32) {
            short8 bfr[3];
#pragma unroll
            for (int nt = 0; nt < 3; nt++) {
                int n = wave * 48 + nt * 16 + l15;
                bfr[nt] = *(const short8*)(Bt + (size_t)n * KP1B + kb + k0 + quad * 8);
            }
#pragma unroll
            for (int mt = 0; mt < 4; mt++) {
                short8 afr = *(const short8*)(&As[mt * 16 + l15][k0 + quad * 8]);
#pragma unroll
                for (int nt = 0; nt < 3; nt++)
                    acc[mt][nt] = __builtin_amdgcn_mfma_f32_16x16x32_bf16(afr, bfr[nt], acc[mt][nt], 0, 0, 0);
            }
        }
    }
#pragma unroll
    for (int mt = 0; mt < 4; mt++) {
#pragma unroll
        for (int nt = 0; nt < 3; nt++) {
            int n = wave * 48 + nt * 16 + l15;
#pragma unroll
            for (int r = 0; r < 4; r++) {
                size_t row = m0 + mt * 16 + quad * 4 + r;
                C[row * HH + n] = f2b(acc[mt][nt][r]);
            }
        }
    }
}

// ---------------------------------------------------------------------------
// Fused: sparse-aggregate + concat-reorder + bias -> BN(per-vertex over B,C)
// -> relu -> (store x | residual update).  One block per vertex u.
// Residual state lives ONLY in bf16 featsB (fp32 master dropped; halving
// updates give ~2^-8 steady-state relative rounding, under tolerance).
// Neighbor list comes as zero-padded cols + precomputed weights vw (no
// pointer-chase, no degree branch).
// MODE 0: write x (bf16).  MODE 1: featsB=(full[:,:192]+x)/2.
// MODE 2: featsB=(featsB+x)/2.  MODE 3: MODE 2 + write feats to d_out (fp32).
template <int MODE>
__global__ __launch_bounds__(256) void k_bn(const bf16* __restrict__ S,
                                            const int* __restrict__ cols,
                                            const float* __restrict__ vw,
                                            const float* __restrict__ bias,
                                            const float* __restrict__ gamma, const float* __restrict__ beta,
                                            const float* __restrict__ feat3, const float* __restrict__ pooled,
                                            bf16* __restrict__ featsB,
                                            bf16* __restrict__ xout, float* __restrict__ dOut) {
    const int u = blockIdx.x;
    const int tid = threadIdx.x;
    __shared__ float red[4];

    int vc[8]; float vi[8];
    {
        int4 c0 = *(const int4*)(cols + u * 8);
        int4 c1 = *(const int4*)(cols + u * 8 + 4);
        floatx4 w0 = *(const floatx4*)(vw + u * 8);
        floatx4 w1 = *(const floatx4*)(vw + u * 8 + 4);
        vc[0] = c0.x; vc[1] = c0.y; vc[2] = c0.z; vc[3] = c0.w;
        vc[4] = c1.x; vc[5] = c1.y; vc[6] = c1.z; vc[7] = c1.w;
        vi[0] = w0[0]; vi[1] = w0[1]; vi[2] = w0[2]; vi[3] = w0[3];
        vi[4] = w1[0]; vi[5] = w1[1]; vi[6] = w1[2]; vi[7] = w1[3];
    }

    float yv[3][8];
    float psum = 0.0f;
#pragma unroll
    for (int i = 0; i < 3; i++) {
        int id = tid + i * 256;
        int b = id / 24, c8 = (id % 24) * 8;
        size_t base = (size_t)b * VV * HH;
        floatx4 bl = *(const floatx4*)(bias + c8);
        floatx4 bh = *(const floatx4*)(bias + c8 + 4);
        float v[8] = {bl[0], bl[1], bl[2], bl[3], bh[0], bh[1], bh[2], bh[3]};
        if (c8 < 128) {
            union { bf16 h[8]; short8 s; } t;
            t.s = *(const short8*)(S + base + (size_t)u * HH + 64 + c8);
#pragma unroll
            for (int j = 0; j < 8; j++) v[j] += b2f(t.h[j]);
        } else {
            int d8 = c8 - 128;
#pragma unroll
            for (int jn = 0; jn < 8; jn++) {
                union { bf16 h[8]; short8 s; } t;
                t.s = *(const short8*)(S + base + (size_t)vc[jn] * HH + d8);
#pragma unroll
                for (int j = 0; j < 8; j++) v[j] += vi[jn] * b2f(t.h[j]);
            }
        }
#pragma unroll
        for (int j = 0; j < 8; j++) { yv[i][j] = v[j]; psum += v[j]; }
    }
    // block reduce (sum)
#pragma unroll
    for (int off = 32; off; off >>= 1) psum += __shfl_down(psum, off, 64);
    if ((tid & 63) == 0) red[tid >> 6] = psum;
    __syncthreads();
    const float mean = (red[0] + red[1] + red[2] + red[3]) * (1.0f / (BB * HH));
    __syncthreads();
    float pvar = 0.0f;
#pragma unroll
    for (int i = 0; i < 3; i++)
#pragma unroll
        for (int j = 0; j < 8; j++) { float t = yv[i][j] - mean; pvar += t * t; }
#pragma unroll
    for (int off = 32; off; off >>= 1) pvar += __shfl_down(pvar, off, 64);
    if ((tid & 63) == 0) red[tid >> 6] = pvar;
    __syncthreads();
    const float rstd = rsqrtf((red[0] + red[1] + red[2] + red[3]) * (1.0f / (BB * HH)) + 1e-5f);
    const float ga = gamma[u], be = beta[u];

#pragma unroll
    for (int i = 0; i < 3; i++) {
        int id = tid + i * 256;
        int b = id / 24, c8 = (id % 24) * 8;
        size_t row = (size_t)b * VV + u;
        float o[8];
#pragma unroll
        for (int j = 0; j < 8; j++)
            o[j] = fmaxf(ga * (yv[i][j] - mean) * rstd + be, 0.0f);
        if constexpr (MODE == 0) {
            union { bf16 h[8]; short8 s; } t;
#pragma unroll
            for (int j = 0; j < 8; j++) t.h[j] = f2b(o[j]);
            *(short8*)(xout + row * HH + c8) = t.s;
        } else {
            float f[8];
            if constexpr (MODE == 1) {
                if (c8 == 0) {
                    f[0] = feat3[row * 3 + 0];
                    f[1] = feat3[row * 3 + 1];
                    f[2] = feat3[row * 3 + 2];
#pragma unroll
                    for (int j = 3; j < 8; j++) f[j] = pooled[row * (size_t)PD + (j - 3)];
                } else {
#pragma unroll
                    for (int j = 0; j < 8; j++) f[j] = pooled[row * (size_t)PD + (c8 + j - 3)];
                }
            } else {
                union { bf16 h[8]; short8 s; } fb;
                fb.s = *(const short8*)(featsB + row * HH + c8);
#pragma unroll
                for (int j = 0; j < 8; j++) f[j] = b2f(fb.h[j]);
            }
            float fn[8];
#pragma unroll
            for (int j = 0; j < 8; j++) fn[j] = (f[j] + o[j]) * 0.5f;
            union { bf16 h[8]; short8 s; } t;
#pragma unroll
            for (int j = 0; j < 8; j++) t.h[j] = f2b(fn[j]);
            *(short8*)(featsB + row * HH + c8) = t.s;
            if constexpr (MODE == 3) {
                *(floatx4*)(dOut + row * HH + c8)     = (floatx4){fn[0], fn[1], fn[2], fn[3]};
                *(floatx4*)(dOut + row * HH + c8 + 4) = (floatx4){fn[4], fn[5], fn[6], fn[7]};
            }
        }
    }
}

// ---------------------------------------------------------------------------
// coords support: SC[row][3] = feats[row][:] @ W15[192][3] (tiny GEMM)
__global__ __launch_bounds__(256) void k_cgemm(const bf16* __restrict__ F,
                                               const float* __restrict__ W15,
                                               float* __restrict__ SC) {
    __shared__ bf16 fs[64 * HH];
    const size_t m0 = (size_t)blockIdx.x * 64;
    const int tid = threadIdx.x;
    for (int c = tid; c < 64 * HH / 8; c += 256) {
        int row = c / 24, c8 = (c % 24) * 8;
        *(short8*)(&fs[row * HH + c8]) = *(const short8*)(F + (m0 + row) * HH + c8);
    }
    __syncthreads();
    for (int idx = tid; idx < 64 * 3; idx += 256) {
        int row = idx / 3, o = idx % 3;
        float acc = 0.0f;
        for (int k = 0; k < HH; k++)
            acc += b2f(fs[row * HH + k]) * W15[k * 3 + o];
        SC[(m0 + row) * 3 + o] = acc;
    }
}

// coords: ch0 = SC[:,2]+b15[0]; ch1/2 = sparse-agg of SC[:,0]/SC[:,1] + b15[1/2]
__global__ void k_cagg(const float* __restrict__ SC, const int* __restrict__ cols,
                       const float* __restrict__ vw,
                       const float* __restrict__ b15, float* __restrict__ out) {
    int gid = blockIdx.x * 256 + threadIdx.x;
    if (gid >= MROWS) return;
    int u = gid % VV;
    int b = gid / VV;
    float s0 = 0.0f, s1 = 0.0f;
#pragma unroll
    for (int j = 0; j < 8; j++) {
        int v = cols[u * 8 + j];
        float w = vw[u * 8 + j];          // 0 for pad lanes
        s0 += w * SC[((size_t)b * VV + v) * 3 + 0];
        s1 += w * SC[((size_t)b * VV + v) * 3 + 1];
    }
    out[(size_t)gid * 3 + 0] = SC[(size_t)gid * 3 + 2] + b15[0];
    out[(size_t)gid * 3 + 1] = s0 + b15[1];
    out[(size_t)gid * 3 + 2] = s1 + b15[2];
}

// ---------------------------------------------------------------------------
extern "C" void kernel_launch(void* const* d_in, const int* in_sizes, int n_in,
                              void* d_out, int out_size, void* d_ws, size_t ws_size,
                              hipStream_t stream) {
    const float* feat   = (const float*)d_in[0];
    const float* pooled = (const float*)d_in[1];
    const float* adj    = (const float*)d_in[2];
    const float* W1     = (const float*)d_in[3];
    const float* b1     = (const float*)d_in[4];
    const float* Wm     = (const float*)d_in[5];
    const float* bm     = (const float*)d_in[6];
    const float* W15    = (const float*)d_in[7];
    const float* b15    = (const float*)d_in[8];
    const float* gamma  = (const float*)d_in[9];
    const float* beta   = (const float*)d_in[10];
    float* outF = (float*)d_out;                    // feats [B,V,192] fp32
    float* outC = outF + (size_t)MROWS * HH;        // coords [B,V,3] fp32

    char* ws = (char*)d_ws;
    size_t off = 0;
    auto alloc = [&](size_t bytes) -> void* {
        void* p = ws + off;
        off = (off + bytes + 255) & ~(size_t)255;
        return p;
    };
    bf16*  sB     = (bf16*) alloc((size_t)MP * HH * 2);   // support intermediate
    bf16*  xB     = (bf16*) alloc((size_t)MP * HH * 2);   // BN output x
    bf16*  featsB = (bf16*) alloc((size_t)MP * HH * 2);   // residual state (bf16 only)
    bf16*  W1t    = (bf16*) alloc((size_t)HH * KP1B * 2);
    bf16*  Wmt    = (bf16*) alloc((size_t)12 * HH * HH * 2);
    float* SC     = (float*)alloc((size_t)MP * 3 * 4);
    int*   degs   = (int*)  alloc(VV * 4);
    int*   colsp  = (int*)  alloc(VV * 8 * 4);
    float* invn   = (float*)alloc(VV * 4);
    float* vw     = (float*)alloc(VV * 8 * 4);
    (void)ws_size; (void)in_sizes; (void)n_in; (void)out_size;

    k_csr<<<VV, 256, 0, stream>>>(adj, degs, colsp, invn);
    int ntr = (HH * KP1B + 12 * HH * HH + VV * 8 + 255) / 256;
    k_trans<<<ntr, 256, 0, stream>>>(W1, Wm, degs, colsp, invn, W1t, Wmt, vw);

    // layer 1: gc1 (K-permuted, K=1056), A read directly from fp32 inputs.
    k_gemm1<<<GR64, 256, 0, stream>>>(feat, pooled, W1t, featsB);
    k_bn<0><<<VV, 256, 0, stream>>>(featsB, colsp, vw, b1,
                                    gamma + 0 * VV, beta + 0 * VV,
                                    nullptr, nullptr, nullptr, xB, nullptr);
    // layer 2: gc2 + residual init  feats = (full[:, :192] + x)/2
    k_gemm<<<GR64, 256, 0, stream>>>(xB, Wmt, sB);
    k_bn<1><<<VV, 256, 0, stream>>>(sB, colsp, vw, bm,
                                    gamma + 1 * VV, beta + 1 * VV,
                                    feat, pooled, featsB, nullptr, nullptr);
    // five residual pairs
    for (int i = 0; i < 5; i++) {
        int la = 2 * i + 1, lb = 2 * i + 2;
        k_gemm<<<GR64, 256, 0, stream>>>(featsB, Wmt + (size_t)la * HH * HH, sB);
        k_bn<0><<<VV, 256, 0, stream>>>(sB, colsp, vw, bm + la * HH,
                                        gamma + (size_t)(la + 1) * VV, beta + (size_t)(la + 1) * VV,
                                        nullptr, nullptr, nullptr, xB, nullptr);
        k_gemm<<<GR64, 256, 0, stream>>>(xB, Wmt + (size_t)lb * HH * HH, sB);
        k_bn<2><<<VV, 256, 0, stream>>>(sB, colsp, vw, bm + lb * HH,
                                        gamma + (size_t)(lb + 1) * VV, beta + (size_t)(lb + 1) * VV,
                                        nullptr, nullptr, featsB, nullptr, nullptr);
    }
    // gc13 + final residual (also writes feats to d_out, fp32)
    k_gemm<<<GR64, 256, 0, stream>>>(featsB, Wmt + (size_t)11 * HH * HH, sB);
    k_bn<3><<<VV, 256, 0, stream>>>(sB, colsp, vw, bm + 11 * HH,
                                    gamma + (size_t)12 * VV, beta + (size_t)12 * VV,
                                    nullptr, nullptr, featsB, nullptr, outF);
    // coords head
    k_cgemm<<<GR64, 256, 0, stream>>>(featsB, W15, SC);
    k_cagg<<<(MROWS + 255) / 256, 256, 0, stream>>>(SC, colsp, vw, b15, outC);
}